// Round 4
// baseline (448.451 us; speedup 1.0000x reference)
//
#include <hip/hip_runtime.h>
#include <hip/hip_bf16.h>

#define N_NODES 20000
#define N_EDGES 320000
#define TOT_E   (N_EDGES + N_NODES)   // 340000 with self loops
#define IN_CH   128
#define HEADS   8
#define CH      33
#define DD      264                   // HEADS*CH
#define OUTW    132
#define NEG     0.2f

#define LDB     272                   // bf16 payload row stride
#define LDA     320                   // hA bf16 row stride, K padded to 10*32
#define NT_HID  18                    // 17 payload tiles + 1 stats tile [was|wad]
#define NT_HEAD 12                    // head gemm tiles (132 -> 192, zero-padded)
#define PK0     4
#define PKH     10
#define PKO     10

typedef unsigned short ushort;
typedef unsigned int uint32;
typedef short bf16x8 __attribute__((ext_vector_type(8)));
typedef float f32x4  __attribute__((ext_vector_type(4)));

__device__ inline void split2(float v, ushort& hi, ushort& lo) {
    __hip_bfloat16 h = __float2bfloat16(v);
    float r = v - __bfloat162float(h);
    __hip_bfloat16 l = __float2bfloat16(r);
    hi = *(ushort*)&h;
    lo = *(ushort*)&l;
}

__device__ inline float bf2f(ushort u) {
    union { unsigned int i; float f; } c;
    c.i = ((unsigned int)u) << 16;
    return c.f;
}

// low ushort of dword -> f32 (shift), high ushort -> f32 (free AND)
__device__ inline float bflo(uint32 d) {
    union { unsigned int i; float f; } c;
    c.i = d << 16;
    return c.f;
}
__device__ inline float bfhi(uint32 d) {
    union { unsigned int i; float f; } c;
    c.i = d & 0xffff0000u;
    return c.f;
}

// ---------------- CSR build ----------------

__global__ void deg_k(const int* __restrict__ ei, int* __restrict__ deg) {
    int e = blockIdx.x * 256 + threadIdx.x;
    if (e >= TOT_E) return;
    int dst = (e < N_EDGES) ? ei[N_EDGES + e] : (e - N_EDGES);
    atomicAdd(&deg[dst], 1);
}

__global__ __launch_bounds__(1024) void scan_k(const int* __restrict__ deg,
                                               int* __restrict__ rowp) {
    __shared__ int part[1024];
    const int PER = 20;
    int t = threadIdx.x;
    int base = t * PER;
    int s = 0;
    for (int i = 0; i < PER; ++i) {
        int idx = base + i;
        if (idx < N_NODES) s += deg[idx];
    }
    part[t] = s;
    __syncthreads();
    for (int off = 1; off < 1024; off <<= 1) {
        int v = 0;
        if (t >= off) v = part[t - off];
        __syncthreads();
        part[t] += v;
        __syncthreads();
    }
    int run = part[t] - s;
    for (int i = 0; i < PER; ++i) {
        int idx = base + i;
        if (idx < N_NODES) { rowp[idx] = run; run += deg[idx]; }
    }
    if (t == 1023) rowp[N_NODES] = part[1023];
}

__global__ void fill_k(const int* __restrict__ ei, const int* __restrict__ rowp,
                       int* __restrict__ cur, int* __restrict__ csr) {
    int e = blockIdx.x * 256 + threadIdx.x;
    if (e >= TOT_E) return;
    int src, dst;
    if (e < N_EDGES) { src = ei[e]; dst = ei[N_EDGES + e]; }
    else             { src = dst = e - N_EDGES; }
    int p = atomicAdd(&cur[dst], 1);
    csr[rowp[dst] + p] = src;
}

// ---------------- input x -> bf16 (into hAhi, stride LDA) ----------------

__global__ void splitx_k(const float* __restrict__ x, ushort* __restrict__ ahi) {
    int idx = blockIdx.x * 256 + threadIdx.x;
    if (idx >= N_NODES * IN_CH) return;
    int n = idx >> 7, k = idx & 127;
    __hip_bfloat16 h = __float2bfloat16(x[idx]);
    ahi[(size_t)n * LDA + k] = *(ushort*)&h;
}

// ---------------- all weights -> fragment-ordered hi/lo bf16, one launch ----------------

__device__ void convw_one(const float* W, const float* a_s, const float* a_d,
                          int K, int NC, int NT, ushort* fhi, ushort* flo, int gid) {
    int p = gid / (NT * 64);
    int rem = gid % (NT * 64);
    int t = rem >> 6, c = rem & 63;
    int kq = c >> 4, m = c & 15;
    int n = t * 16 + m;
    bool stats = (a_s != nullptr) && (t == NT - 1);
    ushort hi8[8], lo8[8];
#pragma unroll
    for (int j = 0; j < 8; ++j) {
        int k = p * 32 + kq * 8 + j;
        float v = 0.f;
        if (k < K) {
            if (stats) {
                const float* av = (m < 8) ? a_s : a_d;
                int h = (m < 8) ? m : m - 8;
                const float* wr = W + (size_t)k * NC + h * CH;
                float s = 0.f;
                for (int cc = 0; cc < CH; ++cc) s += wr[cc] * av[h * CH + cc];
                v = s;
            } else if (n < NC) {
                v = W[(size_t)k * NC + n];
            }
        }
        split2(v, hi8[j], lo8[j]);
    }
    size_t o = ((size_t)gid) * 8;
#pragma unroll
    for (int j = 0; j < 8; ++j) { fhi[o + j] = hi8[j]; flo[o + j] = lo8[j]; }
}

#define SEG0 (PK0 * NT_HID * 64)
#define SEGH (PKH * NT_HID * 64)
#define SEGO (PKO * NT_HEAD * 64)

__global__ void convall_k(
    const float* W0, const float* W1, const float* W2, const float* W3, const float* Wh,
    const float* as0, const float* as1, const float* as2, const float* as3,
    const float* ad0, const float* ad1, const float* ad2, const float* ad3,
    ushort* f0h, ushort* f0l, ushort* f1h, ushort* f1l, ushort* f2h, ushort* f2l,
    ushort* f3h, ushort* f3l, ushort* fhh, ushort* fhl) {
    int gid = blockIdx.x * 256 + threadIdx.x;
    if (gid < SEG0) { convw_one(W0, as0, ad0, IN_CH, DD, NT_HID, f0h, f0l, gid); return; }
    gid -= SEG0;
    if (gid < SEGH) { convw_one(W1, as1, ad1, DD, DD, NT_HID, f1h, f1l, gid); return; }
    gid -= SEGH;
    if (gid < SEGH) { convw_one(W2, as2, ad2, DD, DD, NT_HID, f2h, f2l, gid); return; }
    gid -= SEGH;
    if (gid < SEGH) { convw_one(W3, as3, ad3, DD, DD, NT_HID, f3h, f3l, gid); return; }
    gid -= SEGH;
    if (gid < SEGO) { convw_one(Wh, nullptr, nullptr, DD, OUTW, NT_HEAD, fhh, fhl, gid); }
}

// ---------------- MFMA GEMM, M=128, BK=64, swizzled A LDS, TG=6 (R12-proven) ---------

template<bool USE3, int TG>
__global__ __launch_bounds__(256) void gemm4_k(
    const ushort* __restrict__ Ahi, const ushort* __restrict__ Alo, int kpairs,
    const ushort* __restrict__ Bhi, const ushort* __restrict__ Blo, int NTtot, int statsY,
    ushort* __restrict__ Cb16, float* __restrict__ as_, float* __restrict__ ad_,
    float* __restrict__ C, int ldc, int ncguard, const float* __restrict__ bias) {
    extern __shared__ ushort smem[];
    ushort* AlH = smem;                       // [2][8][512] = 8192 ushorts
    ushort* BlH = smem + 8192;                // [2][TG][512]
    ushort* EXT = smem + 8192 + 2 * TG * 512;
    ushort* AlL = EXT;                        // USE3
    ushort* BlL = EXT + 8192;                 // USE3
    ushort* BstL = EXT;                       // !USE3: stats-tile lo [2][512]

    int tid = threadIdx.x;
    int m0 = blockIdx.x * 128;
    int t0 = blockIdx.y * TG;
    bool sg = ((int)blockIdx.y == statsY);

    f32x4 acc[2][TG];
#pragma unroll
    for (int mt = 0; mt < 2; ++mt)
#pragma unroll
        for (int t = 0; t < TG; ++t) acc[mt][t] = (f32x4){0.f, 0.f, 0.f, 0.f};

    int w = tid >> 6, lane = tid & 63;
    int csA = (lane ^ ((lane >> 4) << 1)) * 8;

    for (int pp = 0; pp < kpairs; ++pp) {
        int nA = USE3 ? 2048 : 1024;
        for (int id = tid; id < nA; id += 256) {
            int hl = id >> 10;
            int cid = id & 1023;
            int mrow = cid >> 3, kq8 = cid & 7;
            int panel = kq8 >> 2, kq = kq8 & 3;
            int gm = m0 + mrow;
            uint4 v = {0, 0, 0, 0};
            if (gm < N_NODES) {
                const ushort* src = (hl ? Alo : Ahi) + (size_t)gm * LDA + pp * 64 + kq8 * 8;
                v = *(const uint4*)src;
            }
            int c = kq * 16 + (mrow & 15);
            int cs = c ^ ((c >> 4) << 1);
            ushort* dst = (hl ? AlL : AlH) + panel * 4096 + (mrow >> 4) * 512 + cs * 8;
            *(uint4*)dst = v;
        }
        for (int id = tid; id < 2 * TG * 64; id += 256) {
            int c = id & 63;
            int r = id >> 6;
            int t = r % TG;
            int panel = r / TG;
            const ushort* src = Bhi + ((size_t)((pp * 2 + panel) * NTtot + t0 + t) * 64 + c) * 8;
            *(uint4*)&BlH[(panel * TG + t) * 512 + c * 8] = *(const uint4*)src;
        }
        if (USE3) {
            for (int id = tid; id < 2 * TG * 64; id += 256) {
                int c = id & 63;
                int r = id >> 6;
                int t = r % TG;
                int panel = r / TG;
                const ushort* src = Blo + ((size_t)((pp * 2 + panel) * NTtot + t0 + t) * 64 + c) * 8;
                *(uint4*)&BlL[(panel * TG + t) * 512 + c * 8] = *(const uint4*)src;
            }
        } else if (sg) {
            for (int id = tid; id < 2 * 64; id += 256) {
                int c = id & 63;
                int panel = id >> 6;
                const ushort* src = Blo + ((size_t)((pp * 2 + panel) * NTtot + t0 + TG - 1) * 64 + c) * 8;
                *(uint4*)&BstL[panel * 512 + c * 8] = *(const uint4*)src;
            }
        }
        __syncthreads();

#pragma unroll
        for (int panel = 0; panel < 2; ++panel) {
            bf16x8 a0 = *(const bf16x8*)&AlH[panel * 4096 + (2 * w) * 512 + csA];
            bf16x8 a1 = *(const bf16x8*)&AlH[panel * 4096 + (2 * w + 1) * 512 + csA];
            bf16x8 l0, l1;
            if (USE3) {
                l0 = *(const bf16x8*)&AlL[panel * 4096 + (2 * w) * 512 + csA];
                l1 = *(const bf16x8*)&AlL[panel * 4096 + (2 * w + 1) * 512 + csA];
            }
#pragma unroll
            for (int t = 0; t < TG; ++t) {
                bf16x8 bh = *(const bf16x8*)&BlH[(panel * TG + t) * 512 + lane * 8];
                acc[0][t] = __builtin_amdgcn_mfma_f32_16x16x32_bf16(a0, bh, acc[0][t], 0, 0, 0);
                acc[1][t] = __builtin_amdgcn_mfma_f32_16x16x32_bf16(a1, bh, acc[1][t], 0, 0, 0);
                if (USE3) {
                    bf16x8 bl = *(const bf16x8*)&BlL[(panel * TG + t) * 512 + lane * 8];
                    acc[0][t] = __builtin_amdgcn_mfma_f32_16x16x32_bf16(a0, bl, acc[0][t], 0, 0, 0);
                    acc[1][t] = __builtin_amdgcn_mfma_f32_16x16x32_bf16(a1, bl, acc[1][t], 0, 0, 0);
                    acc[0][t] = __builtin_amdgcn_mfma_f32_16x16x32_bf16(l0, bh, acc[0][t], 0, 0, 0);
                    acc[1][t] = __builtin_amdgcn_mfma_f32_16x16x32_bf16(l1, bh, acc[1][t], 0, 0, 0);
                } else if (t == TG - 1 && sg) {
                    bf16x8 bst = *(const bf16x8*)&BstL[panel * 512 + lane * 8];
                    acc[0][t] = __builtin_amdgcn_mfma_f32_16x16x32_bf16(a0, bst, acc[0][t], 0, 0, 0);
                    acc[1][t] = __builtin_amdgcn_mfma_f32_16x16x32_bf16(a1, bst, acc[1][t], 0, 0, 0);
                }
            }
        }
        __syncthreads();
    }

    int col = lane & 15;
#pragma unroll
    for (int mt = 0; mt < 2; ++mt) {
        int rbase = m0 + (2 * w + mt) * 16 + ((lane >> 4) << 2);
#pragma unroll
        for (int t = 0; t < TG; ++t) {
            int tg = t0 + t;
#pragma unroll
            for (int r = 0; r < 4; ++r) {
                int gm = rbase + r;
                if (gm >= N_NODES) continue;
                float v = acc[mt][t][r];
                if (C) {
                    int gn = tg * 16 + col;
                    if (gn < ncguard) C[(size_t)gm * ldc + gn] = v + bias[gn];
                } else if (tg < 17) {
                    __hip_bfloat16 bv = __float2bfloat16(v);
                    Cb16[(size_t)gm * LDB + tg * 16 + col] = *(ushort*)&bv;
                } else {
                    if (col < 8) as_[(size_t)gm * 8 + col] = v;
                    else         ad_[(size_t)gm * 8 + col - 8] = v;
                }
            }
        }
    }
}

// ---------------- fused softmax + gather-aggregate: 1 wave / node ----------
// R16: tail channels (256..263) pulled OUT of the inner loop -- lane j loads its
// own edge's 16 tail bytes once per chunk (issued before the barrier, hidden
// under the group loop) and accumulates p8[7]*tail into per-lane partials,
// butterfly-reduced in the epilogue. Inner loop: 4 coalesced row loads + 2 LDS
// reads/edge + 16 FMA. launch_bounds(64,8) pins VGPR <= 64 (the 8-waves/SIMD
// cliff found in R14: 92 VGPR halved occupancy).

__global__ __launch_bounds__(64, 8) void gat_k(
    const ushort* __restrict__ xb, const float* __restrict__ as_,
    const float* __restrict__ ad_, const int* __restrict__ rowp,
    const int* __restrict__ csr, const float* __restrict__ bias,
    ushort* __restrict__ outhi, ushort* __restrict__ outlo) {
    int lane = threadIdx.x;
    int node = blockIdx.x;   // grid is exactly N
    int r0 = rowp[node], dg = rowp[node + 1] - r0;

    __shared__ float lex[64][9];
    __shared__ int   lsrc[64];

    float ad[8];
#pragma unroll
    for (int h = 0; h < 8; ++h) ad[h] = ad_[node * 8 + h];

    // per-lane head mapping: channels 4*lane..4*lane+3 span at most 2 heads
    int ha = (4 * lane) / 33;
    int hb = (4 * lane + 3) / 33;
    bool m1 = ((4 * lane + 1) / 33) != ha;
    bool m2 = ((4 * lane + 2) / 33) != ha;

    float4 a0 = {0.f, 0.f, 0.f, 0.f};
    float4 a1lo = {0.f, 0.f, 0.f, 0.f}, a1hi = {0.f, 0.f, 0.f, 0.f};
    float sm[8] = {0.f, 0.f, 0.f, 0.f, 0.f, 0.f, 0.f, 0.f};

    int nchunks = (dg + 63) >> 6;
    for (int c = 0; c < nchunks; ++c) {
        int base = c << 6, j = base + lane;
        int s = node;
        float p8[8];
#pragma unroll
        for (int h = 0; h < 8; ++h) p8[h] = 0.f;
        if (j < dg) {
            s = csr[r0 + j];
            const float* ap = as_ + (size_t)s * 8;
#pragma unroll
            for (int h = 0; h < 8; ++h) {
                float e = ap[h] + ad[h];
                e = e > 0.f ? e : NEG * e;
                float p = __expf(e);
                p8[h] = p;
                sm[h] += p;
            }
        }
        int myoff = s * LDB;
        lsrc[lane] = myoff;
#pragma unroll
        for (int h = 0; h < 8; ++h) lex[lane][h] = p8[h];

        // edge-parallel tail: this lane's edge, channels 256..263 (16B, one load;
        // issues before the barrier, consumed after the group loop)
        uint4 tt = *(const uint4*)(xb + (size_t)(unsigned)(myoff + 256));
        float w7 = p8[7];

        __builtin_amdgcn_wave_barrier();

        int rem = dg - base;
        int cnt = rem > 64 ? 64 : rem;
        int cnt4 = (cnt + 3) & ~3;
        for (int jj = 0; jj < cnt4; jj += 4) {
            int o0 = lsrc[jj + 0], o1 = lsrc[jj + 1];
            int o2 = lsrc[jj + 2], o3 = lsrc[jj + 3];
            const uint2* p0 = (const uint2*)(xb + (size_t)(unsigned)o0);
            const uint2* p1 = (const uint2*)(xb + (size_t)(unsigned)o1);
            const uint2* p2 = (const uint2*)(xb + (size_t)(unsigned)o2);
            const uint2* p3 = (const uint2*)(xb + (size_t)(unsigned)o3);
            uint2 v0 = p0[lane], v1 = p1[lane], v2 = p2[lane], v3 = p3[lane];
#pragma unroll
            for (int e = 0; e < 4; ++e) {
                const float* xr = lex[jj + e];
                float xa = xr[ha], xbv = xr[hb];
                float x1 = m1 ? xbv : xa;
                float x2 = m2 ? xbv : xa;
                uint2 v = (e == 0) ? v0 : (e == 1) ? v1 : (e == 2) ? v2 : v3;
                a0.x += xa  * bflo(v.x);
                a0.y += x1  * bfhi(v.x);
                a0.z += x2  * bflo(v.y);
                a0.w += xbv * bfhi(v.y);
            }
        }

        // tail accumulate (per-lane edge)
        a1lo.x += w7 * bflo(tt.x);
        a1lo.y += w7 * bfhi(tt.x);
        a1lo.z += w7 * bflo(tt.y);
        a1lo.w += w7 * bfhi(tt.y);
        a1hi.x += w7 * bflo(tt.z);
        a1hi.y += w7 * bfhi(tt.z);
        a1hi.z += w7 * bflo(tt.w);
        a1hi.w += w7 * bfhi(tt.w);

        __builtin_amdgcn_wave_barrier();
    }

    // deferred reductions: sum -> iv[8]; tail partials -> full sums on all lanes
    float iv[8];
#pragma unroll
    for (int h = 0; h < 8; ++h) {
        float s = sm[h];
        for (int off = 32; off; off >>= 1) s += __shfl_xor(s, off, 64);
        iv[h] = 1.0f / (s + 1e-16f);
    }
#pragma unroll
    for (int off = 32; off; off >>= 1) {
        a1lo.x += __shfl_xor(a1lo.x, off, 64);
        a1lo.y += __shfl_xor(a1lo.y, off, 64);
        a1lo.z += __shfl_xor(a1lo.z, off, 64);
        a1lo.w += __shfl_xor(a1lo.w, off, 64);
        a1hi.x += __shfl_xor(a1hi.x, off, 64);
        a1hi.y += __shfl_xor(a1hi.y, off, 64);
        a1hi.z += __shfl_xor(a1hi.z, off, 64);
        a1hi.w += __shfl_xor(a1hi.w, off, 64);
    }

    // epilogue: normalize by iv[head], bias + elu, bf16 (hi) out; lo when requested
#pragma unroll
    for (int k = 0; k < 2; ++k) {
        int i4 = lane + 64 * k;
        if (i4 < 66) {
            float vals[4];
            int hds[4];
            if (k == 0) {
                vals[0] = a0.x; vals[1] = a0.y; vals[2] = a0.z; vals[3] = a0.w;
                hds[0] = ha; hds[1] = m1 ? hb : ha; hds[2] = m2 ? hb : ha; hds[3] = hb;
            } else {
                float4 a = (lane == 0) ? a1lo : a1hi;
                vals[0] = a.x; vals[1] = a.y; vals[2] = a.z; vals[3] = a.w;
                hds[0] = hds[1] = hds[2] = hds[3] = 7;
            }
            ushort hi4[4], lo4[4];
#pragma unroll
            for (int j = 0; j < 4; ++j) {
                float v = vals[j] * iv[hds[j]] + bias[i4 * 4 + j];
                v = v > 0.f ? v : (__expf(v) - 1.f);
                split2(v, hi4[j], lo4[j]);
            }
            size_t o = (size_t)node * LDA + i4 * 4;
            *(ushort4*)(outhi + o) = *(ushort4*)hi4;
            if (outlo) *(ushort4*)(outlo + o) = *(ushort4*)lo4;
        } else if (i4 < 80) {
            ushort4 z = {0, 0, 0, 0};
            size_t o = (size_t)node * LDA + i4 * 4;
            *(ushort4*)(outhi + o) = z;
            if (outlo) *(ushort4*)(outlo + o) = z;
        }
    }
}

// ---------------- launch ----------------

extern "C" void kernel_launch(void* const* d_in, const int* in_sizes, int n_in,
                              void* d_out, int out_size, void* d_ws, size_t ws_size,
                              hipStream_t stream) {
    const float* x  = (const float*)d_in[0];
    const int*   ei = (const int*)d_in[1];
    const float* W[4]  = {(const float*)d_in[2],  (const float*)d_in[6],
                          (const float*)d_in[10], (const float*)d_in[14]};
    const float* As[4] = {(const float*)d_in[3],  (const float*)d_in[7],
                          (const float*)d_in[11], (const float*)d_in[15]};
    const float* Ad[4] = {(const float*)d_in[4],  (const float*)d_in[8],
                          (const float*)d_in[12], (const float*)d_in[16]};
    const float* Bb[4] = {(const float*)d_in[5],  (const float*)d_in[9],
                          (const float*)d_in[13], (const float*)d_in[17]};
    const float* Wh = (const float*)d_in[18];
    const float* bh = (const float*)d_in[19];

    // ---- workspace carve ----
    char* p = (char*)d_ws;
    ushort* hBb  = (ushort*)p;          p += (size_t)N_NODES * LDB * 2;
    ushort* hAhi = (ushort*)p;          p += (size_t)N_NODES * LDA * 2;
    ushort* hAlo = (ushort*)p;          p += (size_t)N_NODES * LDA * 2;
    float* as_  = (float*)p;            p += (size_t)N_NODES * HEADS * 4;
    float* ad_  = (float*)p;            p += (size_t)N_NODES * HEADS * 4;
    const int wsz0 = PK0 * NT_HID * 512;
    const int wszH = PKH * NT_HID * 512;
    const int wszO = PKO * NT_HEAD * 512;
    ushort* wfhi[4]; ushort* wflo[4];
    for (int l = 0; l < 4; ++l) {
        int sz = (l == 0) ? wsz0 : wszH;
        wfhi[l] = (ushort*)p; p += (size_t)sz * 2;
        wflo[l] = (ushort*)p; p += (size_t)sz * 2;
    }
    ushort* whhi = (ushort*)p; p += (size_t)wszO * 2;
    ushort* whlo = (ushort*)p; p += (size_t)wszO * 2;
    int* deg  = (int*)p;  p += N_NODES * 4;
    int* cur  = (int*)p;  p += N_NODES * 4;
    int* rowp = (int*)p;  p += (N_NODES + 1) * 4;
    int* csr  = (int*)p;  p += (size_t)TOT_E * 4;

    // ---- CSR build ----
    hipMemsetAsync(deg, 0, sizeof(int) * 2 * N_NODES, stream);  // deg + cur
    int egrid = (TOT_E + 255) / 256;
    deg_k<<<egrid, 256, 0, stream>>>(ei, deg);
    scan_k<<<1, 1024, 0, stream>>>(deg, rowp);
    fill_k<<<egrid, 256, 0, stream>>>(ei, rowp, cur, csr);

    // ---- weight + input conversion (single launch for all weights) ----
    splitx_k<<<(N_NODES * IN_CH + 255) / 256, 256, 0, stream>>>(x, hAhi);
    {
        int tot = SEG0 + 3 * SEGH + SEGO;
        convall_k<<<(tot + 255) / 256, 256, 0, stream>>>(
            W[0], W[1], W[2], W[3], Wh,
            As[0], As[1], As[2], As[3],
            Ad[0], Ad[1], Ad[2], Ad[3],
            wfhi[0], wflo[0], wfhi[1], wflo[1], wfhi[2], wflo[2],
            wfhi[3], wflo[3], whhi, whlo);
    }

    dim3 gG((N_NODES + 127) / 128, NT_HID / 6);   // 157 x 3
    dim3 gO((N_NODES + 127) / 128, NT_HEAD / 6);  // 157 x 2
    size_t smHid = (size_t)(8192 + 2 * 6 * 512 + 2 * 512) * 2;             // 30720 B
    size_t smHead = (size_t)(8192 + 2 * 6 * 512 + 8192 + 2 * 6 * 512) * 2; // 57344 B

    for (int l = 0; l < 4; ++l) {
        int kpairs = (l == 0) ? PK0 / 2 : PKH / 2;
        gemm4_k<false, 6><<<gG, 256, smHid, stream>>>(hAhi, nullptr, kpairs,
                                                      wfhi[l], wflo[l], NT_HID, 2,
                                                      hBb, as_, ad_, nullptr, 0, 0, nullptr);
        gat_k<<<N_NODES, 64, 0, stream>>>(hBb, as_, ad_, rowp, csr, Bb[l],
                                          hAhi, (l == 3) ? hAlo : nullptr);
    }

    // head readout (3-term) -> fp32 out [N, 132]
    gemm4_k<true, 6><<<gO, 256, smHead, stream>>>(hAhi, hAlo, PKO / 2,
                                                  whhi, whlo, NT_HEAD, -1,
                                                  nullptr, nullptr, nullptr,
                                                  (float*)d_out, OUTW, OUTW, bh);
}

// Round 5
// 423.104 us; speedup vs baseline: 1.0599x; 1.0599x over previous
//
#include <hip/hip_runtime.h>
#include <hip/hip_bf16.h>

#define N_NODES 20000
#define N_EDGES 320000
#define TOT_E   (N_EDGES + N_NODES)   // 340000 with self loops
#define IN_CH   128
#define HEADS   8
#define CH      33
#define DD      264                   // HEADS*CH
#define OUTW    132
#define NEG     0.2f

#define LDB     272                   // bf16 payload row stride
#define LDA     320                   // hA bf16 row stride, K padded to 10*32
#define NT_HID  18                    // 17 payload tiles + 1 stats tile [was|wad]
#define NT_HEAD 12                    // head gemm tiles (132 -> 192, zero-padded)
#define PK0     4
#define PKH     10
#define PKO     10

typedef unsigned short ushort;
typedef unsigned int uint32;
typedef short bf16x8 __attribute__((ext_vector_type(8)));
typedef float f32x4  __attribute__((ext_vector_type(4)));

__device__ inline void split2(float v, ushort& hi, ushort& lo) {
    __hip_bfloat16 h = __float2bfloat16(v);
    float r = v - __bfloat162float(h);
    __hip_bfloat16 l = __float2bfloat16(r);
    hi = *(ushort*)&h;
    lo = *(ushort*)&l;
}

__device__ inline float bf2f(ushort u) {
    union { unsigned int i; float f; } c;
    c.i = ((unsigned int)u) << 16;
    return c.f;
}

// low ushort of dword -> f32 (shift), high ushort -> f32 (free AND)
__device__ inline float bflo(uint32 d) {
    union { unsigned int i; float f; } c;
    c.i = d << 16;
    return c.f;
}
__device__ inline float bfhi(uint32 d) {
    union { unsigned int i; float f; } c;
    c.i = d & 0xffff0000u;
    return c.f;
}

// ---------------- CSR build ----------------

__global__ void deg_k(const int* __restrict__ ei, int* __restrict__ deg) {
    int e = blockIdx.x * 256 + threadIdx.x;
    if (e >= TOT_E) return;
    int dst = (e < N_EDGES) ? ei[N_EDGES + e] : (e - N_EDGES);
    atomicAdd(&deg[dst], 1);
}

__global__ __launch_bounds__(1024) void scan_k(const int* __restrict__ deg,
                                               int* __restrict__ rowp) {
    __shared__ int part[1024];
    const int PER = 20;
    int t = threadIdx.x;
    int base = t * PER;
    int s = 0;
    for (int i = 0; i < PER; ++i) {
        int idx = base + i;
        if (idx < N_NODES) s += deg[idx];
    }
    part[t] = s;
    __syncthreads();
    for (int off = 1; off < 1024; off <<= 1) {
        int v = 0;
        if (t >= off) v = part[t - off];
        __syncthreads();
        part[t] += v;
        __syncthreads();
    }
    int run = part[t] - s;
    for (int i = 0; i < PER; ++i) {
        int idx = base + i;
        if (idx < N_NODES) { rowp[idx] = run; run += deg[idx]; }
    }
    if (t == 1023) rowp[N_NODES] = part[1023];
}

__global__ void fill_k(const int* __restrict__ ei, const int* __restrict__ rowp,
                       int* __restrict__ cur, int* __restrict__ csr) {
    int e = blockIdx.x * 256 + threadIdx.x;
    if (e >= TOT_E) return;
    int src, dst;
    if (e < N_EDGES) { src = ei[e]; dst = ei[N_EDGES + e]; }
    else             { src = dst = e - N_EDGES; }
    int p = atomicAdd(&cur[dst], 1);
    csr[rowp[dst] + p] = src;
}

// ---------------- input x -> bf16 (into hAhi, stride LDA) ----------------

__global__ void splitx_k(const float* __restrict__ x, ushort* __restrict__ ahi) {
    int idx = blockIdx.x * 256 + threadIdx.x;
    if (idx >= N_NODES * IN_CH) return;
    int n = idx >> 7, k = idx & 127;
    __hip_bfloat16 h = __float2bfloat16(x[idx]);
    ahi[(size_t)n * LDA + k] = *(ushort*)&h;
}

// ---------------- all weights -> fragment-ordered hi/lo bf16, one launch ----------------

__device__ void convw_one(const float* W, const float* a_s, const float* a_d,
                          int K, int NC, int NT, ushort* fhi, ushort* flo, int gid) {
    int p = gid / (NT * 64);
    int rem = gid % (NT * 64);
    int t = rem >> 6, c = rem & 63;
    int kq = c >> 4, m = c & 15;
    int n = t * 16 + m;
    bool stats = (a_s != nullptr) && (t == NT - 1);
    ushort hi8[8], lo8[8];
#pragma unroll
    for (int j = 0; j < 8; ++j) {
        int k = p * 32 + kq * 8 + j;
        float v = 0.f;
        if (k < K) {
            if (stats) {
                const float* av = (m < 8) ? a_s : a_d;
                int h = (m < 8) ? m : m - 8;
                const float* wr = W + (size_t)k * NC + h * CH;
                float s = 0.f;
                for (int cc = 0; cc < CH; ++cc) s += wr[cc] * av[h * CH + cc];
                v = s;
            } else if (n < NC) {
                v = W[(size_t)k * NC + n];
            }
        }
        split2(v, hi8[j], lo8[j]);
    }
    size_t o = ((size_t)gid) * 8;
#pragma unroll
    for (int j = 0; j < 8; ++j) { fhi[o + j] = hi8[j]; flo[o + j] = lo8[j]; }
}

#define SEG0 (PK0 * NT_HID * 64)
#define SEGH (PKH * NT_HID * 64)
#define SEGO (PKO * NT_HEAD * 64)

__global__ void convall_k(
    const float* W0, const float* W1, const float* W2, const float* W3, const float* Wh,
    const float* as0, const float* as1, const float* as2, const float* as3,
    const float* ad0, const float* ad1, const float* ad2, const float* ad3,
    ushort* f0h, ushort* f0l, ushort* f1h, ushort* f1l, ushort* f2h, ushort* f2l,
    ushort* f3h, ushort* f3l, ushort* fhh, ushort* fhl) {
    int gid = blockIdx.x * 256 + threadIdx.x;
    if (gid < SEG0) { convw_one(W0, as0, ad0, IN_CH, DD, NT_HID, f0h, f0l, gid); return; }
    gid -= SEG0;
    if (gid < SEGH) { convw_one(W1, as1, ad1, DD, DD, NT_HID, f1h, f1l, gid); return; }
    gid -= SEGH;
    if (gid < SEGH) { convw_one(W2, as2, ad2, DD, DD, NT_HID, f2h, f2l, gid); return; }
    gid -= SEGH;
    if (gid < SEGH) { convw_one(W3, as3, ad3, DD, DD, NT_HID, f3h, f3l, gid); return; }
    gid -= SEGH;
    if (gid < SEGO) { convw_one(Wh, nullptr, nullptr, DD, OUTW, NT_HEAD, fhh, fhl, gid); }
}

// ---------------- MFMA GEMM, M=128, BK=64, swizzled A LDS, TG=6 (R12-proven) ---------

template<bool USE3, int TG>
__global__ __launch_bounds__(256) void gemm4_k(
    const ushort* __restrict__ Ahi, const ushort* __restrict__ Alo, int kpairs,
    const ushort* __restrict__ Bhi, const ushort* __restrict__ Blo, int NTtot, int statsY,
    ushort* __restrict__ Cb16, float* __restrict__ as_, float* __restrict__ ad_,
    float* __restrict__ C, int ldc, int ncguard, const float* __restrict__ bias) {
    extern __shared__ ushort smem[];
    ushort* AlH = smem;                       // [2][8][512] = 8192 ushorts
    ushort* BlH = smem + 8192;                // [2][TG][512]
    ushort* EXT = smem + 8192 + 2 * TG * 512;
    ushort* AlL = EXT;                        // USE3
    ushort* BlL = EXT + 8192;                 // USE3
    ushort* BstL = EXT;                       // !USE3: stats-tile lo [2][512]

    int tid = threadIdx.x;
    int m0 = blockIdx.x * 128;
    int t0 = blockIdx.y * TG;
    bool sg = ((int)blockIdx.y == statsY);

    f32x4 acc[2][TG];
#pragma unroll
    for (int mt = 0; mt < 2; ++mt)
#pragma unroll
        for (int t = 0; t < TG; ++t) acc[mt][t] = (f32x4){0.f, 0.f, 0.f, 0.f};

    int w = tid >> 6, lane = tid & 63;
    int csA = (lane ^ ((lane >> 4) << 1)) * 8;

    for (int pp = 0; pp < kpairs; ++pp) {
        int nA = USE3 ? 2048 : 1024;
        for (int id = tid; id < nA; id += 256) {
            int hl = id >> 10;
            int cid = id & 1023;
            int mrow = cid >> 3, kq8 = cid & 7;
            int panel = kq8 >> 2, kq = kq8 & 3;
            int gm = m0 + mrow;
            uint4 v = {0, 0, 0, 0};
            if (gm < N_NODES) {
                const ushort* src = (hl ? Alo : Ahi) + (size_t)gm * LDA + pp * 64 + kq8 * 8;
                v = *(const uint4*)src;
            }
            int c = kq * 16 + (mrow & 15);
            int cs = c ^ ((c >> 4) << 1);
            ushort* dst = (hl ? AlL : AlH) + panel * 4096 + (mrow >> 4) * 512 + cs * 8;
            *(uint4*)dst = v;
        }
        for (int id = tid; id < 2 * TG * 64; id += 256) {
            int c = id & 63;
            int r = id >> 6;
            int t = r % TG;
            int panel = r / TG;
            const ushort* src = Bhi + ((size_t)((pp * 2 + panel) * NTtot + t0 + t) * 64 + c) * 8;
            *(uint4*)&BlH[(panel * TG + t) * 512 + c * 8] = *(const uint4*)src;
        }
        if (USE3) {
            for (int id = tid; id < 2 * TG * 64; id += 256) {
                int c = id & 63;
                int r = id >> 6;
                int t = r % TG;
                int panel = r / TG;
                const ushort* src = Blo + ((size_t)((pp * 2 + panel) * NTtot + t0 + t) * 64 + c) * 8;
                *(uint4*)&BlL[(panel * TG + t) * 512 + c * 8] = *(const uint4*)src;
            }
        } else if (sg) {
            for (int id = tid; id < 2 * 64; id += 256) {
                int c = id & 63;
                int panel = id >> 6;
                const ushort* src = Blo + ((size_t)((pp * 2 + panel) * NTtot + t0 + TG - 1) * 64 + c) * 8;
                *(uint4*)&BstL[panel * 512 + c * 8] = *(const uint4*)src;
            }
        }
        __syncthreads();

#pragma unroll
        for (int panel = 0; panel < 2; ++panel) {
            bf16x8 a0 = *(const bf16x8*)&AlH[panel * 4096 + (2 * w) * 512 + csA];
            bf16x8 a1 = *(const bf16x8*)&AlH[panel * 4096 + (2 * w + 1) * 512 + csA];
            bf16x8 l0, l1;
            if (USE3) {
                l0 = *(const bf16x8*)&AlL[panel * 4096 + (2 * w) * 512 + csA];
                l1 = *(const bf16x8*)&AlL[panel * 4096 + (2 * w + 1) * 512 + csA];
            }
#pragma unroll
            for (int t = 0; t < TG; ++t) {
                bf16x8 bh = *(const bf16x8*)&BlH[(panel * TG + t) * 512 + lane * 8];
                acc[0][t] = __builtin_amdgcn_mfma_f32_16x16x32_bf16(a0, bh, acc[0][t], 0, 0, 0);
                acc[1][t] = __builtin_amdgcn_mfma_f32_16x16x32_bf16(a1, bh, acc[1][t], 0, 0, 0);
                if (USE3) {
                    bf16x8 bl = *(const bf16x8*)&BlL[(panel * TG + t) * 512 + lane * 8];
                    acc[0][t] = __builtin_amdgcn_mfma_f32_16x16x32_bf16(a0, bl, acc[0][t], 0, 0, 0);
                    acc[1][t] = __builtin_amdgcn_mfma_f32_16x16x32_bf16(a1, bl, acc[1][t], 0, 0, 0);
                    acc[0][t] = __builtin_amdgcn_mfma_f32_16x16x32_bf16(l0, bh, acc[0][t], 0, 0, 0);
                    acc[1][t] = __builtin_amdgcn_mfma_f32_16x16x32_bf16(l1, bh, acc[1][t], 0, 0, 0);
                } else if (t == TG - 1 && sg) {
                    bf16x8 bst = *(const bf16x8*)&BstL[panel * 512 + lane * 8];
                    acc[0][t] = __builtin_amdgcn_mfma_f32_16x16x32_bf16(a0, bst, acc[0][t], 0, 0, 0);
                    acc[1][t] = __builtin_amdgcn_mfma_f32_16x16x32_bf16(a1, bst, acc[1][t], 0, 0, 0);
                }
            }
        }
        __syncthreads();
    }

    int col = lane & 15;
#pragma unroll
    for (int mt = 0; mt < 2; ++mt) {
        int rbase = m0 + (2 * w + mt) * 16 + ((lane >> 4) << 2);
#pragma unroll
        for (int t = 0; t < TG; ++t) {
            int tg = t0 + t;
#pragma unroll
            for (int r = 0; r < 4; ++r) {
                int gm = rbase + r;
                if (gm >= N_NODES) continue;
                float v = acc[mt][t][r];
                if (C) {
                    int gn = tg * 16 + col;
                    if (gn < ncguard) C[(size_t)gm * ldc + gn] = v + bias[gn];
                } else if (tg < 17) {
                    __hip_bfloat16 bv = __float2bfloat16(v);
                    Cb16[(size_t)gm * LDB + tg * 16 + col] = *(ushort*)&bv;
                } else {
                    if (col < 8) as_[(size_t)gm * 8 + col] = v;
                    else         ad_[(size_t)gm * 8 + col - 8] = v;
                }
            }
        }
    }
}

// ---------------- fused softmax + gather-aggregate: 1 wave / node ----------
// R17 = R15 (the 422 us best: no-max softmax, deferred sum butterfly, unified
// single-pass chunk loop, broadcast tail, all-lane tail FMA) + zero-risk
// micro-opts only: dword bflo/bfhi extraction and float4 bias load.
// R14 lesson: VGPR>64 halves occupancy (keep ~52). R16 lesson: per-lane tail
// scatter + epilogue butterfly costs more than the redundant broadcast tail.

__global__ __launch_bounds__(64) void gat_k(
    const ushort* __restrict__ xb, const float* __restrict__ as_,
    const float* __restrict__ ad_, const int* __restrict__ rowp,
    const int* __restrict__ csr, const float* __restrict__ bias,
    ushort* __restrict__ outhi, ushort* __restrict__ outlo) {
    int lane = threadIdx.x;
    int node = blockIdx.x;   // grid is exactly N
    int r0 = rowp[node], dg = rowp[node + 1] - r0;

    __shared__ float lex[64][9];
    __shared__ int   lsrc[64];

    float ad[8];
#pragma unroll
    for (int h = 0; h < 8; ++h) ad[h] = ad_[node * 8 + h];

    // per-lane head mapping: channels 4*lane..4*lane+3 span at most 2 heads
    int ha = (4 * lane) / 33;
    int hb = (4 * lane + 3) / 33;
    bool m1 = ((4 * lane + 1) / 33) != ha;
    bool m2 = ((4 * lane + 2) / 33) != ha;
    // tail channels 256..263 are all head 7

    float4 a0 = {0.f, 0.f, 0.f, 0.f}, a1 = {0.f, 0.f, 0.f, 0.f};
    float sm[8] = {0.f, 0.f, 0.f, 0.f, 0.f, 0.f, 0.f, 0.f};

    int nchunks = (dg + 63) >> 6;
    for (int c = 0; c < nchunks; ++c) {
        int base = c << 6, j = base + lane;
        int s = node;
        float p8[8];
#pragma unroll
        for (int h = 0; h < 8; ++h) p8[h] = 0.f;
        if (j < dg) {
            s = csr[r0 + j];
            const float* ap = as_ + (size_t)s * 8;
#pragma unroll
            for (int h = 0; h < 8; ++h) {
                float e = ap[h] + ad[h];
                e = e > 0.f ? e : NEG * e;
                float p = __expf(e);
                p8[h] = p;
                sm[h] += p;
            }
        }
        lsrc[lane] = s * LDB;   // pre-scaled row offset (ushorts)
#pragma unroll
        for (int h = 0; h < 8; ++h) lex[lane][h] = p8[h];
        __builtin_amdgcn_wave_barrier();

        int rem = dg - base;
        int cnt = rem > 64 ? 64 : rem;
        int cnt4 = (cnt + 3) & ~3;
        for (int jj = 0; jj < cnt4; jj += 4) {
            int o0 = lsrc[jj + 0], o1 = lsrc[jj + 1];
            int o2 = lsrc[jj + 2], o3 = lsrc[jj + 3];
            const uint2* p0 = (const uint2*)(xb + (size_t)(unsigned)o0);
            const uint2* p1 = (const uint2*)(xb + (size_t)(unsigned)o1);
            const uint2* p2 = (const uint2*)(xb + (size_t)(unsigned)o2);
            const uint2* p3 = (const uint2*)(xb + (size_t)(unsigned)o3);
            uint2 v0 = p0[lane], v1 = p1[lane], v2 = p2[lane], v3 = p3[lane];
            // tail: one 32B region per row, lanes split over 2 slots (broadcast)
            uint2 t0 = p0[64 + (lane & 1)], t1 = p1[64 + (lane & 1)];
            uint2 t2 = p2[64 + (lane & 1)], t3 = p3[64 + (lane & 1)];
#pragma unroll
            for (int e = 0; e < 4; ++e) {
                const float* xr = lex[jj + e];
                float xa = xr[ha], xbv = xr[hb], x7 = xr[7];
                float x1 = m1 ? xbv : xa;
                float x2 = m2 ? xbv : xa;
                uint2 v = (e == 0) ? v0 : (e == 1) ? v1 : (e == 2) ? v2 : v3;
                uint2 t = (e == 0) ? t0 : (e == 1) ? t1 : (e == 2) ? t2 : t3;
                a0.x += xa  * bflo(v.x);
                a0.y += x1  * bfhi(v.x);
                a0.z += x2  * bflo(v.y);
                a0.w += xbv * bfhi(v.y);
                a1.x += x7 * bflo(t.x);
                a1.y += x7 * bfhi(t.x);
                a1.z += x7 * bflo(t.y);
                a1.w += x7 * bfhi(t.y);
            }
        }
        __builtin_amdgcn_wave_barrier();
    }

    // deferred sum reduction -> iv[8] (all lanes get full result via butterfly)
    float iv[8];
#pragma unroll
    for (int h = 0; h < 8; ++h) {
        float s = sm[h];
        for (int off = 32; off; off >>= 1) s += __shfl_xor(s, off, 64);
        iv[h] = 1.0f / (s + 1e-16f);
    }

    // epilogue: normalize by iv[head], bias + elu, bf16 (hi) out; lo when requested
#pragma unroll
    for (int k = 0; k < 2; ++k) {
        int i4 = lane + 64 * k;
        if (i4 < 66) {
            float4 a = (k == 0) ? a0 : a1;
            float vals[4] = {a.x, a.y, a.z, a.w};
            int hds[4];
            if (k == 0) {
                hds[0] = ha; hds[1] = m1 ? hb : ha; hds[2] = m2 ? hb : ha; hds[3] = hb;
            } else {
                hds[0] = hds[1] = hds[2] = hds[3] = 7;
            }
            float4 bb = *(const float4*)(bias + i4 * 4);
            float bv4[4] = {bb.x, bb.y, bb.z, bb.w};
            ushort hi4[4], lo4[4];
#pragma unroll
            for (int j = 0; j < 4; ++j) {
                float v = vals[j] * iv[hds[j]] + bv4[j];
                v = v > 0.f ? v : (__expf(v) - 1.f);
                split2(v, hi4[j], lo4[j]);
            }
            size_t o = (size_t)node * LDA + i4 * 4;
            *(ushort4*)(outhi + o) = *(ushort4*)hi4;
            if (outlo) *(ushort4*)(outlo + o) = *(ushort4*)lo4;
        } else if (i4 < 80) {
            ushort4 z = {0, 0, 0, 0};
            size_t o = (size_t)node * LDA + i4 * 4;
            *(ushort4*)(outhi + o) = z;
            if (outlo) *(ushort4*)(outlo + o) = z;
        }
    }
}

// ---------------- launch ----------------

extern "C" void kernel_launch(void* const* d_in, const int* in_sizes, int n_in,
                              void* d_out, int out_size, void* d_ws, size_t ws_size,
                              hipStream_t stream) {
    const float* x  = (const float*)d_in[0];
    const int*   ei = (const int*)d_in[1];
    const float* W[4]  = {(const float*)d_in[2],  (const float*)d_in[6],
                          (const float*)d_in[10], (const float*)d_in[14]};
    const float* As[4] = {(const float*)d_in[3],  (const float*)d_in[7],
                          (const float*)d_in[11], (const float*)d_in[15]};
    const float* Ad[4] = {(const float*)d_in[4],  (const float*)d_in[8],
                          (const float*)d_in[12], (const float*)d_in[16]};
    const float* Bb[4] = {(const float*)d_in[5],  (const float*)d_in[9],
                          (const float*)d_in[13], (const float*)d_in[17]};
    const float* Wh = (const float*)d_in[18];
    const float* bh = (const float*)d_in[19];

    // ---- workspace carve ----
    char* p = (char*)d_ws;
    ushort* hBb  = (ushort*)p;          p += (size_t)N_NODES * LDB * 2;
    ushort* hAhi = (ushort*)p;          p += (size_t)N_NODES * LDA * 2;
    ushort* hAlo = (ushort*)p;          p += (size_t)N_NODES * LDA * 2;
    float* as_  = (float*)p;            p += (size_t)N_NODES * HEADS * 4;
    float* ad_  = (float*)p;            p += (size_t)N_NODES * HEADS * 4;
    const int wsz0 = PK0 * NT_HID * 512;
    const int wszH = PKH * NT_HID * 512;
    const int wszO = PKO * NT_HEAD * 512;
    ushort* wfhi[4]; ushort* wflo[4];
    for (int l = 0; l < 4; ++l) {
        int sz = (l == 0) ? wsz0 : wszH;
        wfhi[l] = (ushort*)p; p += (size_t)sz * 2;
        wflo[l] = (ushort*)p; p += (size_t)sz * 2;
    }
    ushort* whhi = (ushort*)p; p += (size_t)wszO * 2;
    ushort* whlo = (ushort*)p; p += (size_t)wszO * 2;
    int* deg  = (int*)p;  p += N_NODES * 4;
    int* cur  = (int*)p;  p += N_NODES * 4;
    int* rowp = (int*)p;  p += (N_NODES + 1) * 4;
    int* csr  = (int*)p;  p += (size_t)TOT_E * 4;

    // ---- CSR build ----
    hipMemsetAsync(deg, 0, sizeof(int) * 2 * N_NODES, stream);  // deg + cur
    int egrid = (TOT_E + 255) / 256;
    deg_k<<<egrid, 256, 0, stream>>>(ei, deg);
    scan_k<<<1, 1024, 0, stream>>>(deg, rowp);
    fill_k<<<egrid, 256, 0, stream>>>(ei, rowp, cur, csr);

    // ---- weight + input conversion (single launch for all weights) ----
    splitx_k<<<(N_NODES * IN_CH + 255) / 256, 256, 0, stream>>>(x, hAhi);
    {
        int tot = SEG0 + 3 * SEGH + SEGO;
        convall_k<<<(tot + 255) / 256, 256, 0, stream>>>(
            W[0], W[1], W[2], W[3], Wh,
            As[0], As[1], As[2], As[3],
            Ad[0], Ad[1], Ad[2], Ad[3],
            wfhi[0], wflo[0], wfhi[1], wflo[1], wfhi[2], wflo[2],
            wfhi[3], wflo[3], whhi, whlo);
    }

    dim3 gG((N_NODES + 127) / 128, NT_HID / 6);   // 157 x 3
    dim3 gO((N_NODES + 127) / 128, NT_HEAD / 6);  // 157 x 2
    size_t smHid = (size_t)(8192 + 2 * 6 * 512 + 2 * 512) * 2;             // 30720 B
    size_t smHead = (size_t)(8192 + 2 * 6 * 512 + 8192 + 2 * 6 * 512) * 2; // 57344 B

    for (int l = 0; l < 4; ++l) {
        int kpairs = (l == 0) ? PK0 / 2 : PKH / 2;
        gemm4_k<false, 6><<<gG, 256, smHid, stream>>>(hAhi, nullptr, kpairs,
                                                      wfhi[l], wflo[l], NT_HID, 2,
                                                      hBb, as_, ad_, nullptr, 0, 0, nullptr);
        gat_k<<<N_NODES, 64, 0, stream>>>(hBb, as_, ad_, rowp, csr, Bb[l],
                                          hAhi, (l == 3) ? hAlo : nullptr);
    }

    // head readout (3-term) -> fp32 out [N, 132]
    gemm4_k<true, 6><<<gO, 256, smHead, stream>>>(hAhi, hAlo, PKO / 2,
                                                  whhi, whlo, NT_HEAD, -1,
                                                  nullptr, nullptr, nullptr,
                                                  (float*)d_out, OUTW, OUTW, bh);
}

// Round 6
// 417.102 us; speedup vs baseline: 1.0752x; 1.0144x over previous
//
#include <hip/hip_runtime.h>
#include <hip/hip_bf16.h>

#define N_NODES 20000
#define N_EDGES 320000
#define TOT_E   (N_EDGES + N_NODES)   // 340000 with self loops
#define IN_CH   128
#define HEADS   8
#define CH      33
#define DD      264                   // HEADS*CH
#define OUTW    132
#define NEG     0.2f

#define LDB     272                   // bf16 payload row stride (34 uint4 slots)
#define LDA     320                   // hA bf16 row stride, K padded to 10*32
#define NT_HID  18                    // 17 payload tiles + 1 stats tile [was|wad]
#define NT_HEAD 12                    // head gemm tiles (132 -> 192, zero-padded)
#define PK0     4
#define PKH     10
#define PKO     10

typedef unsigned short ushort;
typedef unsigned int uint32;
typedef short bf16x8 __attribute__((ext_vector_type(8)));
typedef float f32x4  __attribute__((ext_vector_type(4)));

__device__ inline void split2(float v, ushort& hi, ushort& lo) {
    __hip_bfloat16 h = __float2bfloat16(v);
    float r = v - __bfloat162float(h);
    __hip_bfloat16 l = __float2bfloat16(r);
    hi = *(ushort*)&h;
    lo = *(ushort*)&l;
}

__device__ inline float bf2f(ushort u) {
    union { unsigned int i; float f; } c;
    c.i = ((unsigned int)u) << 16;
    return c.f;
}

// low ushort of dword -> f32 (shift), high ushort -> f32 (free AND)
__device__ inline float bflo(uint32 d) {
    union { unsigned int i; float f; } c;
    c.i = d << 16;
    return c.f;
}
__device__ inline float bfhi(uint32 d) {
    union { unsigned int i; float f; } c;
    c.i = d & 0xffff0000u;
    return c.f;
}

// ---------------- CSR build ----------------

__global__ void deg_k(const int* __restrict__ ei, int* __restrict__ deg) {
    int e = blockIdx.x * 256 + threadIdx.x;
    if (e >= TOT_E) return;
    int dst = (e < N_EDGES) ? ei[N_EDGES + e] : (e - N_EDGES);
    atomicAdd(&deg[dst], 1);
}

__global__ __launch_bounds__(1024) void scan_k(const int* __restrict__ deg,
                                               int* __restrict__ rowp) {
    __shared__ int part[1024];
    const int PER = 20;
    int t = threadIdx.x;
    int base = t * PER;
    int s = 0;
    for (int i = 0; i < PER; ++i) {
        int idx = base + i;
        if (idx < N_NODES) s += deg[idx];
    }
    part[t] = s;
    __syncthreads();
    for (int off = 1; off < 1024; off <<= 1) {
        int v = 0;
        if (t >= off) v = part[t - off];
        __syncthreads();
        part[t] += v;
        __syncthreads();
    }
    int run = part[t] - s;
    for (int i = 0; i < PER; ++i) {
        int idx = base + i;
        if (idx < N_NODES) { rowp[idx] = run; run += deg[idx]; }
    }
    if (t == 1023) rowp[N_NODES] = part[1023];
}

__global__ void fill_k(const int* __restrict__ ei, const int* __restrict__ rowp,
                       int* __restrict__ cur, int* __restrict__ csr) {
    int e = blockIdx.x * 256 + threadIdx.x;
    if (e >= TOT_E) return;
    int src, dst;
    if (e < N_EDGES) { src = ei[e]; dst = ei[N_EDGES + e]; }
    else             { src = dst = e - N_EDGES; }
    int p = atomicAdd(&cur[dst], 1);
    csr[rowp[dst] + p] = src;
}

// ---------------- input x -> bf16 (into hAhi, stride LDA) ----------------

__global__ void splitx_k(const float* __restrict__ x, ushort* __restrict__ ahi) {
    int idx = blockIdx.x * 256 + threadIdx.x;
    if (idx >= N_NODES * IN_CH) return;
    int n = idx >> 7, k = idx & 127;
    __hip_bfloat16 h = __float2bfloat16(x[idx]);
    ahi[(size_t)n * LDA + k] = *(ushort*)&h;
}

// ---------------- all weights -> fragment-ordered hi/lo bf16, one launch ----------------

__device__ void convw_one(const float* W, const float* a_s, const float* a_d,
                          int K, int NC, int NT, ushort* fhi, ushort* flo, int gid) {
    int p = gid / (NT * 64);
    int rem = gid % (NT * 64);
    int t = rem >> 6, c = rem & 63;
    int kq = c >> 4, m = c & 15;
    int n = t * 16 + m;
    bool stats = (a_s != nullptr) && (t == NT - 1);
    ushort hi8[8], lo8[8];
#pragma unroll
    for (int j = 0; j < 8; ++j) {
        int k = p * 32 + kq * 8 + j;
        float v = 0.f;
        if (k < K) {
            if (stats) {
                const float* av = (m < 8) ? a_s : a_d;
                int h = (m < 8) ? m : m - 8;
                const float* wr = W + (size_t)k * NC + h * CH;
                float s = 0.f;
                for (int cc = 0; cc < CH; ++cc) s += wr[cc] * av[h * CH + cc];
                v = s;
            } else if (n < NC) {
                v = W[(size_t)k * NC + n];
            }
        }
        split2(v, hi8[j], lo8[j]);
    }
    size_t o = ((size_t)gid) * 8;
#pragma unroll
    for (int j = 0; j < 8; ++j) { fhi[o + j] = hi8[j]; flo[o + j] = lo8[j]; }
}

#define SEG0 (PK0 * NT_HID * 64)
#define SEGH (PKH * NT_HID * 64)
#define SEGO (PKO * NT_HEAD * 64)

__global__ void convall_k(
    const float* W0, const float* W1, const float* W2, const float* W3, const float* Wh,
    const float* as0, const float* as1, const float* as2, const float* as3,
    const float* ad0, const float* ad1, const float* ad2, const float* ad3,
    ushort* f0h, ushort* f0l, ushort* f1h, ushort* f1l, ushort* f2h, ushort* f2l,
    ushort* f3h, ushort* f3l, ushort* fhh, ushort* fhl) {
    int gid = blockIdx.x * 256 + threadIdx.x;
    if (gid < SEG0) { convw_one(W0, as0, ad0, IN_CH, DD, NT_HID, f0h, f0l, gid); return; }
    gid -= SEG0;
    if (gid < SEGH) { convw_one(W1, as1, ad1, DD, DD, NT_HID, f1h, f1l, gid); return; }
    gid -= SEGH;
    if (gid < SEGH) { convw_one(W2, as2, ad2, DD, DD, NT_HID, f2h, f2l, gid); return; }
    gid -= SEGH;
    if (gid < SEGH) { convw_one(W3, as3, ad3, DD, DD, NT_HID, f3h, f3l, gid); return; }
    gid -= SEGH;
    if (gid < SEGO) { convw_one(Wh, nullptr, nullptr, DD, OUTW, NT_HEAD, fhh, fhl, gid); }
}

// ---------------- MFMA GEMM, M=128, BK=64, swizzled A LDS, TG=6 (R12-proven) ---------

template<bool USE3, int TG>
__global__ __launch_bounds__(256) void gemm4_k(
    const ushort* __restrict__ Ahi, const ushort* __restrict__ Alo, int kpairs,
    const ushort* __restrict__ Bhi, const ushort* __restrict__ Blo, int NTtot, int statsY,
    ushort* __restrict__ Cb16, float* __restrict__ as_, float* __restrict__ ad_,
    float* __restrict__ C, int ldc, int ncguard, const float* __restrict__ bias) {
    extern __shared__ ushort smem[];
    ushort* AlH = smem;                       // [2][8][512] = 8192 ushorts
    ushort* BlH = smem + 8192;                // [2][TG][512]
    ushort* EXT = smem + 8192 + 2 * TG * 512;
    ushort* AlL = EXT;                        // USE3
    ushort* BlL = EXT + 8192;                 // USE3
    ushort* BstL = EXT;                       // !USE3: stats-tile lo [2][512]

    int tid = threadIdx.x;
    int m0 = blockIdx.x * 128;
    int t0 = blockIdx.y * TG;
    bool sg = ((int)blockIdx.y == statsY);

    f32x4 acc[2][TG];
#pragma unroll
    for (int mt = 0; mt < 2; ++mt)
#pragma unroll
        for (int t = 0; t < TG; ++t) acc[mt][t] = (f32x4){0.f, 0.f, 0.f, 0.f};

    int w = tid >> 6, lane = tid & 63;
    int csA = (lane ^ ((lane >> 4) << 1)) * 8;

    for (int pp = 0; pp < kpairs; ++pp) {
        int nA = USE3 ? 2048 : 1024;
        for (int id = tid; id < nA; id += 256) {
            int hl = id >> 10;
            int cid = id & 1023;
            int mrow = cid >> 3, kq8 = cid & 7;
            int panel = kq8 >> 2, kq = kq8 & 3;
            int gm = m0 + mrow;
            uint4 v = {0, 0, 0, 0};
            if (gm < N_NODES) {
                const ushort* src = (hl ? Alo : Ahi) + (size_t)gm * LDA + pp * 64 + kq8 * 8;
                v = *(const uint4*)src;
            }
            int c = kq * 16 + (mrow & 15);
            int cs = c ^ ((c >> 4) << 1);
            ushort* dst = (hl ? AlL : AlH) + panel * 4096 + (mrow >> 4) * 512 + cs * 8;
            *(uint4*)dst = v;
        }
        for (int id = tid; id < 2 * TG * 64; id += 256) {
            int c = id & 63;
            int r = id >> 6;
            int t = r % TG;
            int panel = r / TG;
            const ushort* src = Bhi + ((size_t)((pp * 2 + panel) * NTtot + t0 + t) * 64 + c) * 8;
            *(uint4*)&BlH[(panel * TG + t) * 512 + c * 8] = *(const uint4*)src;
        }
        if (USE3) {
            for (int id = tid; id < 2 * TG * 64; id += 256) {
                int c = id & 63;
                int r = id >> 6;
                int t = r % TG;
                int panel = r / TG;
                const ushort* src = Blo + ((size_t)((pp * 2 + panel) * NTtot + t0 + t) * 64 + c) * 8;
                *(uint4*)&BlL[(panel * TG + t) * 512 + c * 8] = *(const uint4*)src;
            }
        } else if (sg) {
            for (int id = tid; id < 2 * 64; id += 256) {
                int c = id & 63;
                int panel = id >> 6;
                const ushort* src = Blo + ((size_t)((pp * 2 + panel) * NTtot + t0 + TG - 1) * 64 + c) * 8;
                *(uint4*)&BstL[panel * 512 + c * 8] = *(const uint4*)src;
            }
        }
        __syncthreads();

#pragma unroll
        for (int panel = 0; panel < 2; ++panel) {
            bf16x8 a0 = *(const bf16x8*)&AlH[panel * 4096 + (2 * w) * 512 + csA];
            bf16x8 a1 = *(const bf16x8*)&AlH[panel * 4096 + (2 * w + 1) * 512 + csA];
            bf16x8 l0, l1;
            if (USE3) {
                l0 = *(const bf16x8*)&AlL[panel * 4096 + (2 * w) * 512 + csA];
                l1 = *(const bf16x8*)&AlL[panel * 4096 + (2 * w + 1) * 512 + csA];
            }
#pragma unroll
            for (int t = 0; t < TG; ++t) {
                bf16x8 bh = *(const bf16x8*)&BlH[(panel * TG + t) * 512 + lane * 8];
                acc[0][t] = __builtin_amdgcn_mfma_f32_16x16x32_bf16(a0, bh, acc[0][t], 0, 0, 0);
                acc[1][t] = __builtin_amdgcn_mfma_f32_16x16x32_bf16(a1, bh, acc[1][t], 0, 0, 0);
                if (USE3) {
                    bf16x8 bl = *(const bf16x8*)&BlL[(panel * TG + t) * 512 + lane * 8];
                    acc[0][t] = __builtin_amdgcn_mfma_f32_16x16x32_bf16(a0, bl, acc[0][t], 0, 0, 0);
                    acc[1][t] = __builtin_amdgcn_mfma_f32_16x16x32_bf16(a1, bl, acc[1][t], 0, 0, 0);
                    acc[0][t] = __builtin_amdgcn_mfma_f32_16x16x32_bf16(l0, bh, acc[0][t], 0, 0, 0);
                    acc[1][t] = __builtin_amdgcn_mfma_f32_16x16x32_bf16(l1, bh, acc[1][t], 0, 0, 0);
                } else if (t == TG - 1 && sg) {
                    bf16x8 bst = *(const bf16x8*)&BstL[panel * 512 + lane * 8];
                    acc[0][t] = __builtin_amdgcn_mfma_f32_16x16x32_bf16(a0, bst, acc[0][t], 0, 0, 0);
                    acc[1][t] = __builtin_amdgcn_mfma_f32_16x16x32_bf16(a1, bst, acc[1][t], 0, 0, 0);
                }
            }
        }
        __syncthreads();
    }

    int col = lane & 15;
#pragma unroll
    for (int mt = 0; mt < 2; ++mt) {
        int rbase = m0 + (2 * w + mt) * 16 + ((lane >> 4) << 2);
#pragma unroll
        for (int t = 0; t < TG; ++t) {
            int tg = t0 + t;
#pragma unroll
            for (int r = 0; r < 4; ++r) {
                int gm = rbase + r;
                if (gm >= N_NODES) continue;
                float v = acc[mt][t][r];
                if (C) {
                    int gn = tg * 16 + col;
                    if (gn < ncguard) C[(size_t)gm * ldc + gn] = v + bias[gn];
                } else if (tg < 17) {
                    __hip_bfloat16 bv = __float2bfloat16(v);
                    Cb16[(size_t)gm * LDB + tg * 16 + col] = *(ushort*)&bv;
                } else {
                    if (col < 8) as_[(size_t)gm * 8 + col] = v;
                    else         ad_[(size_t)gm * 8 + col - 8] = v;
                }
            }
        }
    }
}

// ---------------- fused softmax + gather-aggregate: 2 nodes / wave ----------
// R18: half-wave per node. Lanes 0-31 own node 2b, lanes 32-63 own node 2b+1.
// Each half-wave handles 256 main channels at 8 ch/lane (uint4 loads), tail
// ch 256..263 via broadcast uint2 parity slot (same trick as R15). The two
// halves' gather chains are INDEPENDENT -> dual-chain MLP inside the wave
// without the prefetch registers that killed R14. Wave count halves (10000);
// each inner iteration retires 8 edge-gathers (4 per node). Keeps the R15
// no-max softmax + deferred sum (butterfly offsets <=16 stay within halves).

__global__ __launch_bounds__(64) void gat_k(
    const ushort* __restrict__ xb, const float* __restrict__ as_,
    const float* __restrict__ ad_, const int* __restrict__ rowp,
    const int* __restrict__ csr, const float* __restrict__ bias,
    ushort* __restrict__ outhi, ushort* __restrict__ outlo) {
    int lane = threadIdx.x;
    int half = lane >> 5, l32 = lane & 31;
    int node = blockIdx.x * 2 + half;       // grid is exactly N/2
    int r0 = rowp[node], dg = rowp[node + 1] - r0;

    __shared__ float lex[2][32][9];
    __shared__ int   lsrc[2][32];

    float ad[8];
#pragma unroll
    for (int h = 0; h < 8; ++h) ad[h] = ad_[node * 8 + h];

    // this lane's 8 channels: cb..cb+7; they span at most 2 heads
    int cb = l32 * 8;
    int ha = cb / 33;
    int hb = (cb + 7) / 33;
    bool mm[8];
#pragma unroll
    for (int j = 0; j < 8; ++j) mm[j] = ((cb + j) / 33) != ha;

    float a0[8];
#pragma unroll
    for (int j = 0; j < 8; ++j) a0[j] = 0.f;
    float a1[4] = {0.f, 0.f, 0.f, 0.f};   // tail: even l32 ch 256-259, odd 260-263
    float sm[8] = {0.f, 0.f, 0.f, 0.f, 0.f, 0.f, 0.f, 0.f};

    int mych = (dg + 31) >> 5;
    int och = __shfl_xor(mych, 32, 64);
    int maxch = mych > och ? mych : och;

    for (int c = 0; c < maxch; ++c) {
        int base = c << 5, j = base + l32;
        int s = node;
        float p8[8];
#pragma unroll
        for (int h = 0; h < 8; ++h) p8[h] = 0.f;
        if (j < dg) {
            s = csr[r0 + j];
            const float* ap = as_ + (size_t)s * 8;
#pragma unroll
            for (int h = 0; h < 8; ++h) {
                float e = ap[h] + ad[h];
                e = e > 0.f ? e : NEG * e;
                float p = __expf(e);
                p8[h] = p;
                sm[h] += p;
            }
        }
        lsrc[half][l32] = s * LDB;   // pre-scaled row offset (ushorts)
#pragma unroll
        for (int h = 0; h < 8; ++h) lex[half][l32][h] = p8[h];
        __builtin_amdgcn_wave_barrier();

        int rem = dg - base;
        int cnt = rem < 0 ? 0 : (rem > 32 ? 32 : rem);
        int cnt4 = (cnt + 3) & ~3;
        for (int jj = 0; jj < cnt4; jj += 4) {
            int o0 = lsrc[half][jj + 0], o1 = lsrc[half][jj + 1];
            int o2 = lsrc[half][jj + 2], o3 = lsrc[half][jj + 3];
            const uint4* p0 = (const uint4*)(xb + (size_t)(unsigned)o0);
            const uint4* p1 = (const uint4*)(xb + (size_t)(unsigned)o1);
            const uint4* p2 = (const uint4*)(xb + (size_t)(unsigned)o2);
            const uint4* p3 = (const uint4*)(xb + (size_t)(unsigned)o3);
            uint4 v0 = p0[l32], v1 = p1[l32], v2 = p2[l32], v3 = p3[l32];
            // tail: uint2 slots 64/65 (ch 256-263), parity-split broadcast
            const uint2* q0 = (const uint2*)p0;
            const uint2* q1 = (const uint2*)p1;
            const uint2* q2 = (const uint2*)p2;
            const uint2* q3 = (const uint2*)p3;
            uint2 t0 = q0[64 + (l32 & 1)], t1 = q1[64 + (l32 & 1)];
            uint2 t2 = q2[64 + (l32 & 1)], t3 = q3[64 + (l32 & 1)];
#pragma unroll
            for (int e = 0; e < 4; ++e) {
                const float* xr = lex[half][jj + e];
                float xa = xr[ha], xbv = xr[hb], x7 = xr[7];
                uint4 v = (e == 0) ? v0 : (e == 1) ? v1 : (e == 2) ? v2 : v3;
                uint2 t = (e == 0) ? t0 : (e == 1) ? t1 : (e == 2) ? t2 : t3;
                a0[0] += (mm[0] ? xbv : xa) * bflo(v.x);
                a0[1] += (mm[1] ? xbv : xa) * bfhi(v.x);
                a0[2] += (mm[2] ? xbv : xa) * bflo(v.y);
                a0[3] += (mm[3] ? xbv : xa) * bfhi(v.y);
                a0[4] += (mm[4] ? xbv : xa) * bflo(v.z);
                a0[5] += (mm[5] ? xbv : xa) * bfhi(v.z);
                a0[6] += (mm[6] ? xbv : xa) * bflo(v.w);
                a0[7] += (mm[7] ? xbv : xa) * bfhi(v.w);
                a1[0] += x7 * bflo(t.x);
                a1[1] += x7 * bfhi(t.x);
                a1[2] += x7 * bflo(t.y);
                a1[3] += x7 * bfhi(t.y);
            }
        }
        __builtin_amdgcn_wave_barrier();
    }

    // deferred sum reduction -> iv[8]; xor offsets <=16 stay within each half
    float iv[8];
#pragma unroll
    for (int h = 0; h < 8; ++h) {
        float s = sm[h];
        for (int off = 16; off; off >>= 1) s += __shfl_xor(s, off, 64);
        iv[h] = 1.0f / (s + 1e-16f);
    }

    // epilogue: normalize, bias + elu, bf16 out (hi; lo when requested)
    // main: lane's 8 ch at cb (16B aligned); tail: l32 0/1 write ch 256-263;
    // zero-pad ch 264-319 (7 uint4 slots) via lanes l32 2..8
    {
        float iva = iv[ha], ivb = iv[hb];
        ushort hi8[8], lo8[8];
        float4 b0 = *(const float4*)(bias + cb);
        float4 b1 = *(const float4*)(bias + cb + 4);
        float bv4[8] = {b0.x, b0.y, b0.z, b0.w, b1.x, b1.y, b1.z, b1.w};
#pragma unroll
        for (int j = 0; j < 8; ++j) {
            float v = a0[j] * (mm[j] ? ivb : iva) + bv4[j];
            v = v > 0.f ? v : (__expf(v) - 1.f);
            split2(v, hi8[j], lo8[j]);
        }
        size_t o = (size_t)node * LDA + cb;
        *(ushort4*)(outhi + o) = *(ushort4*)&hi8[0];
        *(ushort4*)(outhi + o + 4) = *(ushort4*)&hi8[4];
        if (outlo) {
            *(ushort4*)(outlo + o) = *(ushort4*)&lo8[0];
            *(ushort4*)(outlo + o + 4) = *(ushort4*)&lo8[4];
        }
    }
    if (l32 < 2) {
        // tail ch 256+4*l32 .. 259+4*l32 (a1 identical across same-parity lanes)
        ushort hi4[4], lo4[4];
        float4 bt = *(const float4*)(bias + 256 + l32 * 4);
        float bv4[4] = {bt.x, bt.y, bt.z, bt.w};
#pragma unroll
        for (int j = 0; j < 4; ++j) {
            float v = a1[j] * iv[7] + bv4[j];
            v = v > 0.f ? v : (__expf(v) - 1.f);
            split2(v, hi4[j], lo4[j]);
        }
        size_t o = (size_t)node * LDA + 256 + l32 * 4;
        *(ushort4*)(outhi + o) = *(ushort4*)hi4;
        if (outlo) *(ushort4*)(outlo + o) = *(ushort4*)lo4;
    } else if (l32 < 9) {
        // zero K-pad: ushort slots [264, 320) = uint4 slots 33..39 of the row
        ushort4 z = {0, 0, 0, 0};
        size_t o = (size_t)node * LDA + 264 + (l32 - 2) * 8;
        *(ushort4*)(outhi + o) = z;
        *(ushort4*)(outhi + o + 4) = z;
        if (outlo) {
            *(ushort4*)(outlo + o) = z;
            *(ushort4*)(outlo + o + 4) = z;
        }
    }
}

// ---------------- launch ----------------

extern "C" void kernel_launch(void* const* d_in, const int* in_sizes, int n_in,
                              void* d_out, int out_size, void* d_ws, size_t ws_size,
                              hipStream_t stream) {
    const float* x  = (const float*)d_in[0];
    const int*   ei = (const int*)d_in[1];
    const float* W[4]  = {(const float*)d_in[2],  (const float*)d_in[6],
                          (const float*)d_in[10], (const float*)d_in[14]};
    const float* As[4] = {(const float*)d_in[3],  (const float*)d_in[7],
                          (const float*)d_in[11], (const float*)d_in[15]};
    const float* Ad[4] = {(const float*)d_in[4],  (const float*)d_in[8],
                          (const float*)d_in[12], (const float*)d_in[16]};
    const float* Bb[4] = {(const float*)d_in[5],  (const float*)d_in[9],
                          (const float*)d_in[13], (const float*)d_in[17]};
    const float* Wh = (const float*)d_in[18];
    const float* bh = (const float*)d_in[19];

    // ---- workspace carve ----
    char* p = (char*)d_ws;
    ushort* hBb  = (ushort*)p;          p += (size_t)N_NODES * LDB * 2;
    ushort* hAhi = (ushort*)p;          p += (size_t)N_NODES * LDA * 2;
    ushort* hAlo = (ushort*)p;          p += (size_t)N_NODES * LDA * 2;
    float* as_  = (float*)p;            p += (size_t)N_NODES * HEADS * 4;
    float* ad_  = (float*)p;            p += (size_t)N_NODES * HEADS * 4;
    const int wsz0 = PK0 * NT_HID * 512;
    const int wszH = PKH * NT_HID * 512;
    const int wszO = PKO * NT_HEAD * 512;
    ushort* wfhi[4]; ushort* wflo[4];
    for (int l = 0; l < 4; ++l) {
        int sz = (l == 0) ? wsz0 : wszH;
        wfhi[l] = (ushort*)p; p += (size_t)sz * 2;
        wflo[l] = (ushort*)p; p += (size_t)sz * 2;
    }
    ushort* whhi = (ushort*)p; p += (size_t)wszO * 2;
    ushort* whlo = (ushort*)p; p += (size_t)wszO * 2;
    int* deg  = (int*)p;  p += N_NODES * 4;
    int* cur  = (int*)p;  p += N_NODES * 4;
    int* rowp = (int*)p;  p += (N_NODES + 1) * 4;
    int* csr  = (int*)p;  p += (size_t)TOT_E * 4;

    // ---- CSR build ----
    hipMemsetAsync(deg, 0, sizeof(int) * 2 * N_NODES, stream);  // deg + cur
    int egrid = (TOT_E + 255) / 256;
    deg_k<<<egrid, 256, 0, stream>>>(ei, deg);
    scan_k<<<1, 1024, 0, stream>>>(deg, rowp);
    fill_k<<<egrid, 256, 0, stream>>>(ei, rowp, cur, csr);

    // ---- weight + input conversion (single launch for all weights) ----
    splitx_k<<<(N_NODES * IN_CH + 255) / 256, 256, 0, stream>>>(x, hAhi);
    {
        int tot = SEG0 + 3 * SEGH + SEGO;
        convall_k<<<(tot + 255) / 256, 256, 0, stream>>>(
            W[0], W[1], W[2], W[3], Wh,
            As[0], As[1], As[2], As[3],
            Ad[0], Ad[1], Ad[2], Ad[3],
            wfhi[0], wflo[0], wfhi[1], wflo[1], wfhi[2], wflo[2],
            wfhi[3], wflo[3], whhi, whlo);
    }

    dim3 gG((N_NODES + 127) / 128, NT_HID / 6);   // 157 x 3
    dim3 gO((N_NODES + 127) / 128, NT_HEAD / 6);  // 157 x 2
    size_t smHid = (size_t)(8192 + 2 * 6 * 512 + 2 * 512) * 2;             // 30720 B
    size_t smHead = (size_t)(8192 + 2 * 6 * 512 + 8192 + 2 * 6 * 512) * 2; // 57344 B

    for (int l = 0; l < 4; ++l) {
        int kpairs = (l == 0) ? PK0 / 2 : PKH / 2;
        gemm4_k<false, 6><<<gG, 256, smHid, stream>>>(hAhi, nullptr, kpairs,
                                                      wfhi[l], wflo[l], NT_HID, 2,
                                                      hBb, as_, ad_, nullptr, 0, 0, nullptr);
        gat_k<<<N_NODES / 2, 64, 0, stream>>>(hBb, as_, ad_, rowp, csr, Bb[l],
                                              hAhi, (l == 3) ? hAlo : nullptr);
    }

    // head readout (3-term) -> fp32 out [N, 132]
    gemm4_k<true, 6><<<gO, 256, smHead, stream>>>(hAhi, hAlo, PKO / 2,
                                                  whhi, whlo, NT_HEAD, -1,
                                                  nullptr, nullptr, nullptr,
                                                  (float*)d_out, OUTW, OUTW, bh);
}

// Round 7
// 385.947 us; speedup vs baseline: 1.1620x; 1.0807x over previous
//
#include <hip/hip_runtime.h>
#include <hip/hip_bf16.h>

#define N_NODES 20000
#define N_EDGES 320000
#define TOT_E   (N_EDGES + N_NODES)   // 340000 with self loops
#define IN_CH   128
#define HEADS   8
#define CH      33
#define DD      264                   // HEADS*CH
#define OUTW    132
#define NEG     0.2f

#define LDB     272                   // bf16 payload row stride (34 uint4 slots)
#define LDA     320                   // hA bf16 row stride, K padded to 10*32
#define NT_HID  18                    // 17 payload tiles + 1 stats tile [was|wad]
#define NT_HEAD 12                    // head gemm tiles (132 -> 192, zero-padded)
#define PK0     4
#define PKH     10
#define PKO     10

typedef unsigned short ushort;
typedef unsigned int uint32;
typedef short bf16x8 __attribute__((ext_vector_type(8)));
typedef float f32x4  __attribute__((ext_vector_type(4)));

__device__ inline void split2(float v, ushort& hi, ushort& lo) {
    __hip_bfloat16 h = __float2bfloat16(v);
    float r = v - __bfloat162float(h);
    __hip_bfloat16 l = __float2bfloat16(r);
    hi = *(ushort*)&h;
    lo = *(ushort*)&l;
}

__device__ inline float bf2f(ushort u) {
    union { unsigned int i; float f; } c;
    c.i = ((unsigned int)u) << 16;
    return c.f;
}

// low ushort of dword -> f32 (shift), high ushort -> f32 (free AND)
__device__ inline float bflo(uint32 d) {
    union { unsigned int i; float f; } c;
    c.i = d << 16;
    return c.f;
}
__device__ inline float bfhi(uint32 d) {
    union { unsigned int i; float f; } c;
    c.i = d & 0xffff0000u;
    return c.f;
}

// async global->LDS, 16B per lane; LDS dst is wave-uniform base + lane*16
__device__ __forceinline__ void ld_lds16(const ushort* g, ushort* l) {
    __builtin_amdgcn_global_load_lds(
        (const __attribute__((address_space(1))) void*)g,
        (__attribute__((address_space(3))) void*)l, 16, 0, 0);
}

// ---------------- CSR build ----------------

__global__ void deg_k(const int* __restrict__ ei, int* __restrict__ deg) {
    int e = blockIdx.x * 256 + threadIdx.x;
    if (e >= TOT_E) return;
    int dst = (e < N_EDGES) ? ei[N_EDGES + e] : (e - N_EDGES);
    atomicAdd(&deg[dst], 1);
}

__global__ __launch_bounds__(1024) void scan_k(const int* __restrict__ deg,
                                               int* __restrict__ rowp) {
    __shared__ int part[1024];
    const int PER = 20;
    int t = threadIdx.x;
    int base = t * PER;
    int s = 0;
    for (int i = 0; i < PER; ++i) {
        int idx = base + i;
        if (idx < N_NODES) s += deg[idx];
    }
    part[t] = s;
    __syncthreads();
    for (int off = 1; off < 1024; off <<= 1) {
        int v = 0;
        if (t >= off) v = part[t - off];
        __syncthreads();
        part[t] += v;
        __syncthreads();
    }
    int run = part[t] - s;
    for (int i = 0; i < PER; ++i) {
        int idx = base + i;
        if (idx < N_NODES) { rowp[idx] = run; run += deg[idx]; }
    }
    if (t == 1023) rowp[N_NODES] = part[1023];
}

__global__ void fill_k(const int* __restrict__ ei, const int* __restrict__ rowp,
                       int* __restrict__ cur, int* __restrict__ csr) {
    int e = blockIdx.x * 256 + threadIdx.x;
    if (e >= TOT_E) return;
    int src, dst;
    if (e < N_EDGES) { src = ei[e]; dst = ei[N_EDGES + e]; }
    else             { src = dst = e - N_EDGES; }
    int p = atomicAdd(&cur[dst], 1);
    csr[rowp[dst] + p] = src;
}

// ---------------- input x -> bf16 (into hAhi, stride LDA) ----------------

__global__ void splitx_k(const float* __restrict__ x, ushort* __restrict__ ahi) {
    int idx = blockIdx.x * 256 + threadIdx.x;
    if (idx >= N_NODES * IN_CH) return;
    int n = idx >> 7, k = idx & 127;
    __hip_bfloat16 h = __float2bfloat16(x[idx]);
    ahi[(size_t)n * LDA + k] = *(ushort*)&h;
}

// ---------------- all weights -> fragment-ordered hi/lo bf16, one launch ----------------

__device__ void convw_one(const float* W, const float* a_s, const float* a_d,
                          int K, int NC, int NT, ushort* fhi, ushort* flo, int gid) {
    int p = gid / (NT * 64);
    int rem = gid % (NT * 64);
    int t = rem >> 6, c = rem & 63;
    int kq = c >> 4, m = c & 15;
    int n = t * 16 + m;
    bool stats = (a_s != nullptr) && (t == NT - 1);
    ushort hi8[8], lo8[8];
#pragma unroll
    for (int j = 0; j < 8; ++j) {
        int k = p * 32 + kq * 8 + j;
        float v = 0.f;
        if (k < K) {
            if (stats) {
                const float* av = (m < 8) ? a_s : a_d;
                int h = (m < 8) ? m : m - 8;
                const float* wr = W + (size_t)k * NC + h * CH;
                float s = 0.f;
                for (int cc = 0; cc < CH; ++cc) s += wr[cc] * av[h * CH + cc];
                v = s;
            } else if (n < NC) {
                v = W[(size_t)k * NC + n];
            }
        }
        split2(v, hi8[j], lo8[j]);
    }
    size_t o = ((size_t)gid) * 8;
#pragma unroll
    for (int j = 0; j < 8; ++j) { fhi[o + j] = hi8[j]; flo[o + j] = lo8[j]; }
}

#define SEG0 (PK0 * NT_HID * 64)
#define SEGH (PKH * NT_HID * 64)
#define SEGO (PKO * NT_HEAD * 64)

__global__ void convall_k(
    const float* W0, const float* W1, const float* W2, const float* W3, const float* Wh,
    const float* as0, const float* as1, const float* as2, const float* as3,
    const float* ad0, const float* ad1, const float* ad2, const float* ad3,
    ushort* f0h, ushort* f0l, ushort* f1h, ushort* f1l, ushort* f2h, ushort* f2l,
    ushort* f3h, ushort* f3l, ushort* fhh, ushort* fhl) {
    int gid = blockIdx.x * 256 + threadIdx.x;
    if (gid < SEG0) { convw_one(W0, as0, ad0, IN_CH, DD, NT_HID, f0h, f0l, gid); return; }
    gid -= SEG0;
    if (gid < SEGH) { convw_one(W1, as1, ad1, DD, DD, NT_HID, f1h, f1l, gid); return; }
    gid -= SEGH;
    if (gid < SEGH) { convw_one(W2, as2, ad2, DD, DD, NT_HID, f2h, f2l, gid); return; }
    gid -= SEGH;
    if (gid < SEGH) { convw_one(W3, as3, ad3, DD, DD, NT_HID, f3h, f3l, gid); return; }
    gid -= SEGH;
    if (gid < SEGO) { convw_one(Wh, nullptr, nullptr, DD, OUTW, NT_HEAD, fhh, fhl, gid); }
}

// ---------------- MFMA GEMM, M=128, BK=64, swizzled A LDS, TG=6 ---------
// R19: staging via global_load_lds width=16 (guide Common-mistake #1).
// A keeps bit-identical LDS layout: the cs-XOR is an involution, so lane s of
// each LDS row sources (kq = s>>4, m15 = (s&15)^((s>>4)<<1)); OOB rows clamp
// to N_NODES-1 (outputs discarded by epilogue guard). 1D grid, y-adjacent
// ordering so blocks sharing an A-stripe land on the same XCD.

template<bool USE3, int TG>
__global__ __launch_bounds__(256) void gemm4_k(
    const ushort* __restrict__ Ahi, const ushort* __restrict__ Alo, int kpairs,
    const ushort* __restrict__ Bhi, const ushort* __restrict__ Blo, int NTtot, int statsY,
    ushort* __restrict__ Cb16, float* __restrict__ as_, float* __restrict__ ad_,
    float* __restrict__ C, int ldc, int ncguard, const float* __restrict__ bias) {
    extern __shared__ ushort smem[];
    ushort* AlH = smem;                       // [2][8][512] = 8192 ushorts
    ushort* BlH = smem + 8192;                // [2][TG][512]
    ushort* EXT = smem + 8192 + 2 * TG * 512;
    ushort* AlL = EXT;                        // USE3
    ushort* BlL = EXT + 8192;                 // USE3
    ushort* BstL = EXT;                       // !USE3: stats-tile lo [2][512]

    int tid = threadIdx.x;
    int ngy = NTtot / TG;
    int m0 = (blockIdx.x / ngy) * 128;
    int by = blockIdx.x % ngy;
    int t0 = by * TG;
    bool sg = (by == statsY);

    f32x4 acc[2][TG];
#pragma unroll
    for (int mt = 0; mt < 2; ++mt)
#pragma unroll
        for (int t = 0; t < TG; ++t) acc[mt][t] = (f32x4){0.f, 0.f, 0.f, 0.f};

    int w = tid >> 6, lane = tid & 63;
    int csA = (lane ^ ((lane >> 4) << 1)) * 8;

    // A-stage source mapping for this lane (slot = lane of each LDS row)
    int kqA = lane >> 4;
    int m15 = (lane ^ (kqA << 1)) & 15;

    for (int pp = 0; pp < kpairs; ++pp) {
        // ---- A tiles: 16 rows hi (+16 lo if USE3), one gload_lds per row ----
        int nArows = USE3 ? 32 : 16;
        for (int r = w; r < nArows; r += 4) {
            int hl = r >> 4;
            int panel = (r >> 3) & 1;
            int mrow16 = r & 7;
            int gm = m0 + mrow16 * 16 + m15;
            if (gm > N_NODES - 1) gm = N_NODES - 1;
            const ushort* g = (hl ? Alo : Ahi) + (size_t)gm * LDA + pp * 64 + panel * 32 + kqA * 8;
            ushort* l = (hl ? AlL : AlH) + (panel * 8 + mrow16) * 512;
            ld_lds16(g, l);
        }
        // ---- B tiles: 2*TG rows, linear ----
        for (int r = w; r < 2 * TG; r += 4) {
            int panel = r / TG, t = r % TG;
            size_t row = (size_t)((pp * 2 + panel) * NTtot + t0 + t) * 512;
            ld_lds16(Bhi + row + lane * 8, &BlH[r * 512]);
            if (USE3) ld_lds16(Blo + row + lane * 8, &BlL[r * 512]);
        }
        if (!USE3 && sg && w < 2) {
            int panel = w;
            size_t row = (size_t)((pp * 2 + panel) * NTtot + t0 + TG - 1) * 512;
            ld_lds16(Blo + row + lane * 8, &BstL[panel * 512]);
        }
        __syncthreads();

#pragma unroll
        for (int panel = 0; panel < 2; ++panel) {
            bf16x8 a0 = *(const bf16x8*)&AlH[panel * 4096 + (2 * w) * 512 + csA];
            bf16x8 a1 = *(const bf16x8*)&AlH[panel * 4096 + (2 * w + 1) * 512 + csA];
            bf16x8 l0, l1;
            if (USE3) {
                l0 = *(const bf16x8*)&AlL[panel * 4096 + (2 * w) * 512 + csA];
                l1 = *(const bf16x8*)&AlL[panel * 4096 + (2 * w + 1) * 512 + csA];
            }
#pragma unroll
            for (int t = 0; t < TG; ++t) {
                bf16x8 bh = *(const bf16x8*)&BlH[(panel * TG + t) * 512 + lane * 8];
                acc[0][t] = __builtin_amdgcn_mfma_f32_16x16x32_bf16(a0, bh, acc[0][t], 0, 0, 0);
                acc[1][t] = __builtin_amdgcn_mfma_f32_16x16x32_bf16(a1, bh, acc[1][t], 0, 0, 0);
                if (USE3) {
                    bf16x8 bl = *(const bf16x8*)&BlL[(panel * TG + t) * 512 + lane * 8];
                    acc[0][t] = __builtin_amdgcn_mfma_f32_16x16x32_bf16(a0, bl, acc[0][t], 0, 0, 0);
                    acc[1][t] = __builtin_amdgcn_mfma_f32_16x16x32_bf16(a1, bl, acc[1][t], 0, 0, 0);
                    acc[0][t] = __builtin_amdgcn_mfma_f32_16x16x32_bf16(l0, bh, acc[0][t], 0, 0, 0);
                    acc[1][t] = __builtin_amdgcn_mfma_f32_16x16x32_bf16(l1, bh, acc[1][t], 0, 0, 0);
                } else if (t == TG - 1 && sg) {
                    bf16x8 bst = *(const bf16x8*)&BstL[panel * 512 + lane * 8];
                    acc[0][t] = __builtin_amdgcn_mfma_f32_16x16x32_bf16(a0, bst, acc[0][t], 0, 0, 0);
                    acc[1][t] = __builtin_amdgcn_mfma_f32_16x16x32_bf16(a1, bst, acc[1][t], 0, 0, 0);
                }
            }
        }
        __syncthreads();
    }

    int col = lane & 15;
#pragma unroll
    for (int mt = 0; mt < 2; ++mt) {
        int rbase = m0 + (2 * w + mt) * 16 + ((lane >> 4) << 2);
#pragma unroll
        for (int t = 0; t < TG; ++t) {
            int tg = t0 + t;
#pragma unroll
            for (int r = 0; r < 4; ++r) {
                int gm = rbase + r;
                if (gm >= N_NODES) continue;
                float v = acc[mt][t][r];
                if (C) {
                    int gn = tg * 16 + col;
                    if (gn < ncguard) C[(size_t)gm * ldc + gn] = v + bias[gn];
                } else if (tg < 17) {
                    __hip_bfloat16 bv = __float2bfloat16(v);
                    Cb16[(size_t)gm * LDB + tg * 16 + col] = *(ushort*)&bv;
                } else {
                    if (col < 8) as_[(size_t)gm * 8 + col] = v;
                    else         ad_[(size_t)gm * 8 + col - 8] = v;
                }
            }
        }
    }
}

// ---------------- fused softmax + gather-aggregate: 2 nodes / wave (R18) ----------

__global__ __launch_bounds__(64) void gat_k(
    const ushort* __restrict__ xb, const float* __restrict__ as_,
    const float* __restrict__ ad_, const int* __restrict__ rowp,
    const int* __restrict__ csr, const float* __restrict__ bias,
    ushort* __restrict__ outhi, ushort* __restrict__ outlo) {
    int lane = threadIdx.x;
    int half = lane >> 5, l32 = lane & 31;
    int node = blockIdx.x * 2 + half;       // grid is exactly N/2
    int r0 = rowp[node], dg = rowp[node + 1] - r0;

    __shared__ float lex[2][32][9];
    __shared__ int   lsrc[2][32];

    float ad[8];
#pragma unroll
    for (int h = 0; h < 8; ++h) ad[h] = ad_[node * 8 + h];

    // this lane's 8 channels: cb..cb+7; they span at most 2 heads
    int cb = l32 * 8;
    int ha = cb / 33;
    int hb = (cb + 7) / 33;
    bool mm[8];
#pragma unroll
    for (int j = 0; j < 8; ++j) mm[j] = ((cb + j) / 33) != ha;

    float a0[8];
#pragma unroll
    for (int j = 0; j < 8; ++j) a0[j] = 0.f;
    float a1[4] = {0.f, 0.f, 0.f, 0.f};   // tail: even l32 ch 256-259, odd 260-263
    float sm[8] = {0.f, 0.f, 0.f, 0.f, 0.f, 0.f, 0.f, 0.f};

    int mych = (dg + 31) >> 5;
    int och = __shfl_xor(mych, 32, 64);
    int maxch = mych > och ? mych : och;

    for (int c = 0; c < maxch; ++c) {
        int base = c << 5, j = base + l32;
        int s = node;
        float p8[8];
#pragma unroll
        for (int h = 0; h < 8; ++h) p8[h] = 0.f;
        if (j < dg) {
            s = csr[r0 + j];
            const float* ap = as_ + (size_t)s * 8;
#pragma unroll
            for (int h = 0; h < 8; ++h) {
                float e = ap[h] + ad[h];
                e = e > 0.f ? e : NEG * e;
                float p = __expf(e);
                p8[h] = p;
                sm[h] += p;
            }
        }
        lsrc[half][l32] = s * LDB;   // pre-scaled row offset (ushorts)
#pragma unroll
        for (int h = 0; h < 8; ++h) lex[half][l32][h] = p8[h];
        __builtin_amdgcn_wave_barrier();

        int rem = dg - base;
        int cnt = rem < 0 ? 0 : (rem > 32 ? 32 : rem);
        int cnt4 = (cnt + 3) & ~3;
        for (int jj = 0; jj < cnt4; jj += 4) {
            int o0 = lsrc[half][jj + 0], o1 = lsrc[half][jj + 1];
            int o2 = lsrc[half][jj + 2], o3 = lsrc[half][jj + 3];
            const uint4* p0 = (const uint4*)(xb + (size_t)(unsigned)o0);
            const uint4* p1 = (const uint4*)(xb + (size_t)(unsigned)o1);
            const uint4* p2 = (const uint4*)(xb + (size_t)(unsigned)o2);
            const uint4* p3 = (const uint4*)(xb + (size_t)(unsigned)o3);
            uint4 v0 = p0[l32], v1 = p1[l32], v2 = p2[l32], v3 = p3[l32];
            // tail: uint2 slots 64/65 (ch 256-263), parity-split broadcast
            const uint2* q0 = (const uint2*)p0;
            const uint2* q1 = (const uint2*)p1;
            const uint2* q2 = (const uint2*)p2;
            const uint2* q3 = (const uint2*)p3;
            uint2 t0 = q0[64 + (l32 & 1)], t1 = q1[64 + (l32 & 1)];
            uint2 t2 = q2[64 + (l32 & 1)], t3 = q3[64 + (l32 & 1)];
#pragma unroll
            for (int e = 0; e < 4; ++e) {
                const float* xr = lex[half][jj + e];
                float xa = xr[ha], xbv = xr[hb], x7 = xr[7];
                uint4 v = (e == 0) ? v0 : (e == 1) ? v1 : (e == 2) ? v2 : v3;
                uint2 t = (e == 0) ? t0 : (e == 1) ? t1 : (e == 2) ? t2 : t3;
                a0[0] += (mm[0] ? xbv : xa) * bflo(v.x);
                a0[1] += (mm[1] ? xbv : xa) * bfhi(v.x);
                a0[2] += (mm[2] ? xbv : xa) * bflo(v.y);
                a0[3] += (mm[3] ? xbv : xa) * bfhi(v.y);
                a0[4] += (mm[4] ? xbv : xa) * bflo(v.z);
                a0[5] += (mm[5] ? xbv : xa) * bfhi(v.z);
                a0[6] += (mm[6] ? xbv : xa) * bflo(v.w);
                a0[7] += (mm[7] ? xbv : xa) * bfhi(v.w);
                a1[0] += x7 * bflo(t.x);
                a1[1] += x7 * bfhi(t.x);
                a1[2] += x7 * bflo(t.y);
                a1[3] += x7 * bfhi(t.y);
            }
        }
        __builtin_amdgcn_wave_barrier();
    }

    // deferred sum reduction -> iv[8]; xor offsets <=16 stay within each half
    float iv[8];
#pragma unroll
    for (int h = 0; h < 8; ++h) {
        float s = sm[h];
        for (int off = 16; off; off >>= 1) s += __shfl_xor(s, off, 64);
        iv[h] = 1.0f / (s + 1e-16f);
    }

    // epilogue: normalize, bias + elu, bf16 out (hi; lo when requested)
    {
        float iva = iv[ha], ivb = iv[hb];
        ushort hi8[8], lo8[8];
        float4 b0 = *(const float4*)(bias + cb);
        float4 b1 = *(const float4*)(bias + cb + 4);
        float bv4[8] = {b0.x, b0.y, b0.z, b0.w, b1.x, b1.y, b1.z, b1.w};
#pragma unroll
        for (int j = 0; j < 8; ++j) {
            float v = a0[j] * (mm[j] ? ivb : iva) + bv4[j];
            v = v > 0.f ? v : (__expf(v) - 1.f);
            split2(v, hi8[j], lo8[j]);
        }
        size_t o = (size_t)node * LDA + cb;
        *(ushort4*)(outhi + o) = *(ushort4*)&hi8[0];
        *(ushort4*)(outhi + o + 4) = *(ushort4*)&hi8[4];
        if (outlo) {
            *(ushort4*)(outlo + o) = *(ushort4*)&lo8[0];
            *(ushort4*)(outlo + o + 4) = *(ushort4*)&lo8[4];
        }
    }
    if (l32 < 2) {
        ushort hi4[4], lo4[4];
        float4 bt = *(const float4*)(bias + 256 + l32 * 4);
        float bv4[4] = {bt.x, bt.y, bt.z, bt.w};
#pragma unroll
        for (int j = 0; j < 4; ++j) {
            float v = a1[j] * iv[7] + bv4[j];
            v = v > 0.f ? v : (__expf(v) - 1.f);
            split2(v, hi4[j], lo4[j]);
        }
        size_t o = (size_t)node * LDA + 256 + l32 * 4;
        *(ushort4*)(outhi + o) = *(ushort4*)hi4;
        if (outlo) *(ushort4*)(outlo + o) = *(ushort4*)lo4;
    } else if (l32 < 9) {
        ushort4 z = {0, 0, 0, 0};
        size_t o = (size_t)node * LDA + 264 + (l32 - 2) * 8;
        *(ushort4*)(outhi + o) = z;
        *(ushort4*)(outhi + o + 4) = z;
        if (outlo) {
            *(ushort4*)(outlo + o) = z;
            *(ushort4*)(outlo + o + 4) = z;
        }
    }
}

// ---------------- launch ----------------

extern "C" void kernel_launch(void* const* d_in, const int* in_sizes, int n_in,
                              void* d_out, int out_size, void* d_ws, size_t ws_size,
                              hipStream_t stream) {
    const float* x  = (const float*)d_in[0];
    const int*   ei = (const int*)d_in[1];
    const float* W[4]  = {(const float*)d_in[2],  (const float*)d_in[6],
                          (const float*)d_in[10], (const float*)d_in[14]};
    const float* As[4] = {(const float*)d_in[3],  (const float*)d_in[7],
                          (const float*)d_in[11], (const float*)d_in[15]};
    const float* Ad[4] = {(const float*)d_in[4],  (const float*)d_in[8],
                          (const float*)d_in[12], (const float*)d_in[16]};
    const float* Bb[4] = {(const float*)d_in[5],  (const float*)d_in[9],
                          (const float*)d_in[13], (const float*)d_in[17]};
    const float* Wh = (const float*)d_in[18];
    const float* bh = (const float*)d_in[19];

    // ---- workspace carve ----
    char* p = (char*)d_ws;
    ushort* hBb  = (ushort*)p;          p += (size_t)N_NODES * LDB * 2;
    ushort* hAhi = (ushort*)p;          p += (size_t)N_NODES * LDA * 2;
    ushort* hAlo = (ushort*)p;          p += (size_t)N_NODES * LDA * 2;
    float* as_  = (float*)p;            p += (size_t)N_NODES * HEADS * 4;
    float* ad_  = (float*)p;            p += (size_t)N_NODES * HEADS * 4;
    const int wsz0 = PK0 * NT_HID * 512;
    const int wszH = PKH * NT_HID * 512;
    const int wszO = PKO * NT_HEAD * 512;
    ushort* wfhi[4]; ushort* wflo[4];
    for (int l = 0; l < 4; ++l) {
        int sz = (l == 0) ? wsz0 : wszH;
        wfhi[l] = (ushort*)p; p += (size_t)sz * 2;
        wflo[l] = (ushort*)p; p += (size_t)sz * 2;
    }
    ushort* whhi = (ushort*)p; p += (size_t)wszO * 2;
    ushort* whlo = (ushort*)p; p += (size_t)wszO * 2;
    int* deg  = (int*)p;  p += N_NODES * 4;
    int* cur  = (int*)p;  p += N_NODES * 4;
    int* rowp = (int*)p;  p += (N_NODES + 1) * 4;
    int* csr  = (int*)p;  p += (size_t)TOT_E * 4;

    // ---- CSR build ----
    hipMemsetAsync(deg, 0, sizeof(int) * 2 * N_NODES, stream);  // deg + cur
    int egrid = (TOT_E + 255) / 256;
    deg_k<<<egrid, 256, 0, stream>>>(ei, deg);
    scan_k<<<1, 1024, 0, stream>>>(deg, rowp);
    fill_k<<<egrid, 256, 0, stream>>>(ei, rowp, cur, csr);

    // ---- weight + input conversion (single launch for all weights) ----
    splitx_k<<<(N_NODES * IN_CH + 255) / 256, 256, 0, stream>>>(x, hAhi);
    {
        int tot = SEG0 + 3 * SEGH + SEGO;
        convall_k<<<(tot + 255) / 256, 256, 0, stream>>>(
            W[0], W[1], W[2], W[3], Wh,
            As[0], As[1], As[2], As[3],
            Ad[0], Ad[1], Ad[2], Ad[3],
            wfhi[0], wflo[0], wfhi[1], wflo[1], wfhi[2], wflo[2],
            wfhi[3], wflo[3], whhi, whlo);
    }

    int nmb = (N_NODES + 127) / 128;              // 157
    int gG = nmb * (NT_HID / 6);                  // 471, y-adjacent
    int gO = nmb * (NT_HEAD / 6);                 // 314
    size_t smHid = (size_t)(8192 + 2 * 6 * 512 + 2 * 512) * 2;             // 30720 B
    size_t smHead = (size_t)(8192 + 2 * 6 * 512 + 8192 + 2 * 6 * 512) * 2; // 57344 B

    for (int l = 0; l < 4; ++l) {
        int kpairs = (l == 0) ? PK0 / 2 : PKH / 2;
        gemm4_k<false, 6><<<gG, 256, smHid, stream>>>(hAhi, nullptr, kpairs,
                                                      wfhi[l], wflo[l], NT_HID, 2,
                                                      hBb, as_, ad_, nullptr, 0, 0, nullptr);
        gat_k<<<N_NODES / 2, 64, 0, stream>>>(hBb, as_, ad_, rowp, csr, Bb[l],
                                              hAhi, (l == 3) ? hAlo : nullptr);
    }

    // head readout (3-term) -> fp32 out [N, 132]
    gemm4_k<true, 6><<<gO, 256, smHead, stream>>>(hAhi, hAlo, PKO / 2,
                                                  whhi, whlo, NT_HEAD, -1,
                                                  nullptr, nullptr, nullptr,
                                                  (float*)d_out, OUTW, OUTW, bh);
}